// Round 2
// baseline (1094.365 us; speedup 1.0000x reference)
//
#include <hip/hip_runtime.h>
#include <hip/hip_bf16.h>
#include <math.h>

#define T_TOK 8192
#define DM 1024
#define DFF 4096
#define NE 8
#define HROWS 16512
#define MAX_TILES 136

typedef __attribute__((ext_vector_type(8))) short bf16x8;
typedef __attribute__((ext_vector_type(4))) float f32x4;

__device__ __forceinline__ void async16(const void* g, void* l) {
  __builtin_amdgcn_global_load_lds((const __attribute__((address_space(1))) void*)g,
                                   (__attribute__((address_space(3))) void*)l, 16, 0, 0);
}

__device__ __forceinline__ unsigned short f2b(float f) {
  __hip_bfloat16 h = __float2bfloat16(f);
  return *reinterpret_cast<unsigned short*>(&h);
}

__device__ __forceinline__ float gelu_tanh(float v) {
  return 0.5f * v * (1.0f + tanhf(0.7978845608028654f * (v + 0.044715f * v * v * v)));
}

// ---------------- cast x (fp32 -> bf16), 4 elems/thread ----------------
__global__ void cast_x_kernel(const float* __restrict__ in, unsigned short* __restrict__ out) {
  int i = blockIdx.x * blockDim.x + threadIdx.x;
  float4 v = reinterpret_cast<const float4*>(in)[i];
  ushort4 o;
  o.x = f2b(v.x); o.y = f2b(v.y); o.z = f2b(v.z); o.w = f2b(v.w);
  reinterpret_cast<ushort4*>(out)[i] = o;
}

// ---------------- transpose + cast: in fp32 [E][R][C] -> out bf16 [E][C][R] ----------------
__global__ void transpose_cast_kernel(const float* __restrict__ in, unsigned short* __restrict__ out,
                                      int R, int C) {
  __shared__ float tile[32][33];
  int e = blockIdx.z;
  int r0 = blockIdx.y * 32, c0 = blockIdx.x * 32;
  const float* src = in + (size_t)e * R * C;
  unsigned short* dst = out + (size_t)e * R * C;
  int tx = threadIdx.x, ty = threadIdx.y;  // (32,8)
#pragma unroll
  for (int i = 0; i < 32; i += 8) tile[ty + i][tx] = src[(size_t)(r0 + ty + i) * C + c0 + tx];
  __syncthreads();
#pragma unroll
  for (int i = 0; i < 32; i += 8) dst[(size_t)(c0 + ty + i) * R + r0 + tx] = f2b(tile[tx][ty + i]);
}

// ---------------- router GEMM1: A = tanh(X @ Wg1 + bg1), fp32, 128x128x16 tiles ----------------
__global__ __launch_bounds__(256) void router_gemm1_kernel(
    const float* __restrict__ X, const float* __restrict__ Wg1,
    const float* __restrict__ bg1, float* __restrict__ Ar) {
  __shared__ float As[16][132];
  __shared__ float Bs[16][132];
  const int tid = threadIdx.x;
  const int m0 = blockIdx.y * 128, n0 = blockIdx.x * 128;
  const int tm = (tid & 15) * 8;
  const int tn = (tid >> 4) * 8;
  const int lm = tid >> 1;
  const int lk = (tid & 1) * 8;
  const int bk = tid >> 4;
  const int bn = (tid & 15) * 8;
  float acc[8][8] = {};
  const float* xrow = X + (size_t)(m0 + lm) * DM + lk;
  const float* brow = Wg1 + (size_t)bk * DM + n0 + bn;
  for (int k0 = 0; k0 < DM; k0 += 16) {
    float4 a0 = *(const float4*)(xrow + k0);
    float4 a1 = *(const float4*)(xrow + k0 + 4);
    float4 b0 = *(const float4*)(brow + (size_t)k0 * DM);
    float4 b1 = *(const float4*)(brow + (size_t)k0 * DM + 4);
    __syncthreads();
    As[lk + 0][lm] = a0.x; As[lk + 1][lm] = a0.y; As[lk + 2][lm] = a0.z; As[lk + 3][lm] = a0.w;
    As[lk + 4][lm] = a1.x; As[lk + 5][lm] = a1.y; As[lk + 6][lm] = a1.z; As[lk + 7][lm] = a1.w;
    *(float4*)&Bs[bk][bn] = b0;
    *(float4*)&Bs[bk][bn + 4] = b1;
    __syncthreads();
#pragma unroll
    for (int k = 0; k < 16; k++) {
      float av[8], bv[8];
      *(float4*)&av[0] = *(const float4*)&As[k][tm];
      *(float4*)&av[4] = *(const float4*)&As[k][tm + 4];
      *(float4*)&bv[0] = *(const float4*)&Bs[k][tn];
      *(float4*)&bv[4] = *(const float4*)&Bs[k][tn + 4];
#pragma unroll
      for (int i = 0; i < 8; i++)
#pragma unroll
        for (int j = 0; j < 8; j++) acc[i][j] = fmaf(av[i], bv[j], acc[i][j]);
    }
  }
#pragma unroll
  for (int i = 0; i < 8; i++) {
    int gm = m0 + tm + i;
    size_t rb = (size_t)gm * DM;
#pragma unroll
    for (int j = 0; j < 8; j++) {
      int gn = n0 + tn + j;
      Ar[rb + gn] = tanhf(acc[i][j] + bg1[gn]);
    }
  }
}

// ---------------- router top-k: one wave per token ----------------
__global__ void router_topk_kernel(const float* __restrict__ Ar, const float* __restrict__ Wg2,
                                   int* __restrict__ tIdx, float* __restrict__ tGate,
                                   int* __restrict__ counts) {
  int gt = (blockIdx.x * blockDim.x + threadIdx.x) >> 6;
  int lane = threadIdx.x & 63;
  if (gt >= T_TOK) return;
  const float* a = Ar + (size_t)gt * DM;
  float p[NE] = {0.f, 0.f, 0.f, 0.f, 0.f, 0.f, 0.f, 0.f};
  for (int i = 0; i < 16; i++) {
    int k = i * 64 + lane;
    float av = a[k];
    float4 w0 = *(const float4*)(Wg2 + (size_t)k * NE);
    float4 w1 = *(const float4*)(Wg2 + (size_t)k * NE + 4);
    p[0] = fmaf(av, w0.x, p[0]); p[1] = fmaf(av, w0.y, p[1]);
    p[2] = fmaf(av, w0.z, p[2]); p[3] = fmaf(av, w0.w, p[3]);
    p[4] = fmaf(av, w1.x, p[4]); p[5] = fmaf(av, w1.y, p[5]);
    p[6] = fmaf(av, w1.z, p[6]); p[7] = fmaf(av, w1.w, p[7]);
  }
#pragma unroll
  for (int off = 32; off > 0; off >>= 1)
#pragma unroll
    for (int e = 0; e < NE; e++) p[e] += __shfl_xor(p[e], off);
  if (lane == 0) {
    float mx = p[0];
#pragma unroll
    for (int e = 1; e < NE; e++) mx = fmaxf(mx, p[e]);
    float ex[NE], s = 0.f;
#pragma unroll
    for (int e = 0; e < NE; e++) { ex[e] = expf(p[e] - mx); s += ex[e]; }
    float inv = 1.0f / s;
    float v1 = -1e30f, v2 = -1e30f; int i1 = 0, i2 = 1;
#pragma unroll
    for (int e = 0; e < NE; e++) {
      float v = ex[e] * inv;
      if (v > v1) { v2 = v1; i2 = i1; v1 = v; i1 = e; }
      else if (v > v2) { v2 = v; i2 = e; }
    }
    float den = 1.0f / (v1 + v2 + 1e-6f);
    tIdx[2 * gt] = i1; tIdx[2 * gt + 1] = i2;
    tGate[2 * gt] = v1 * den; tGate[2 * gt + 1] = v2 * den;
    atomicAdd(&counts[i1], 1);
    atomicAdd(&counts[i2], 1);
  }
}

// ---------------- prefix sums + tile descriptors (single thread) ----------------
__global__ void build_tiles_kernel(const int* __restrict__ counts, int* __restrict__ offsets,
                                   int4* __restrict__ desc, int* __restrict__ nTiles) {
  if (threadIdx.x != 0 || blockIdx.x != 0) return;
  int off = 0, nt = 0;
  for (int e = 0; e < NE; e++) {
    offsets[e] = off;
    int c = counts[e];
    if (c < 0) c = 0;
    if (c > 2 * T_TOK) c = 2 * T_TOK;
    for (int r = 0; r < c && nt < MAX_TILES; r += 128) {
      int v = c - r; if (v > 128) v = 128;
      desc[nt++] = make_int4(e, off + r, v, 0);
    }
    off += c;
    if (off > 2 * T_TOK) off = 2 * T_TOK;
  }
  offsets[NE] = off;
  *nTiles = nt;
}

// ---------------- scatter tokens into expert-grouped lists ----------------
__global__ void scatter_kernel(const int* __restrict__ tIdx, const float* __restrict__ tGate,
                               const int* __restrict__ offsets, int* __restrict__ fill,
                               int* __restrict__ tokList, float* __restrict__ gateList) {
  int id = blockIdx.x * blockDim.x + threadIdx.x;
  if (id >= 2 * T_TOK) return;
  int e = tIdx[id] & 7;
  int pos = atomicAdd(&fill[e], 1);
  int row = offsets[e] + pos;
  if (row < 0 || row >= 2 * T_TOK) return;
  tokList[row] = id >> 1;
  gateList[row] = tGate[id];
}

// ---------------- FFN1: h = gelu(gather(xb) @ W1_e), bf16 MFMA 128x128 tile ----------------
__global__ __launch_bounds__(256) void ffn1_kernel(
    const unsigned short* __restrict__ xb, const unsigned short* __restrict__ w1t,
    const int* __restrict__ tokList, const int4* __restrict__ desc,
    const int* __restrict__ nTiles, unsigned short* __restrict__ h) {
  if ((int)blockIdx.x >= *nTiles) return;
  int4 d = desc[blockIdx.x];
  const int e = d.x, rowStart = d.y, valid = d.z;
  const int n0 = blockIdx.y * 128;

  __shared__ __align__(16) unsigned short Abuf[128 * 32];
  __shared__ __align__(16) unsigned short Bbuf[128 * 32];
  __shared__ int tIds[128];

  const int tid = threadIdx.x;
  const int lane = tid & 63;
  const int w = tid >> 6;

  if (tid < 128) tIds[tid] = tokList[rowStart + tid] & (T_TOK - 1);
  __syncthreads();

  const int r0 = w * 16 + (lane >> 2);
  const int r1 = r0 + 64;
  const int sp = lane & 3;
  const int k0s = (sp ^ ((r0 >> 1) & 3)) * 8;
  const int k1s = (sp ^ ((r1 >> 1) & 3)) * 8;

  const unsigned short* ga0 = xb + (size_t)tIds[r0] * DM + k0s;
  const unsigned short* ga1 = xb + (size_t)tIds[r1] * DM + k1s;
  const unsigned short* gb0 = w1t + ((size_t)e * DFF + n0 + r0) * DM + k0s;
  const unsigned short* gb1 = w1t + ((size_t)e * DFF + n0 + r1) * DM + k1s;

  char* la0 = (char*)Abuf + w * 1024;
  char* la1 = (char*)Abuf + 4096 + w * 1024;
  char* lb0 = (char*)Bbuf + w * 1024;
  char* lb1 = (char*)Bbuf + 4096 + w * 1024;

  const int wr = (w >> 1) * 64, wc = (w & 1) * 64;
  const int l15 = lane & 15, ls = lane >> 4;

  f32x4 zero = {0.f, 0.f, 0.f, 0.f};
  f32x4 acc[4][4];
#pragma unroll
  for (int i = 0; i < 4; i++)
#pragma unroll
    for (int j = 0; j < 4; j++) acc[i][j] = zero;

  for (int kt = 0; kt < DM; kt += 32) {
    async16(ga0 + kt, la0);
    async16(ga1 + kt, la1);
    async16(gb0 + kt, lb0);
    async16(gb1 + kt, lb1);
    __syncthreads();
    bf16x8 af[4], bfr[4];
#pragma unroll
    for (int i = 0; i < 4; i++) {
      int ar = wr + i * 16 + l15;
      af[i] = *(const bf16x8*)((const char*)Abuf + ar * 64 + ((ls ^ ((ar >> 1) & 3)) << 4));
    }
#pragma unroll
    for (int j = 0; j < 4; j++) {
      int br = wc + j * 16 + l15;
      bfr[j] = *(const bf16x8*)((const char*)Bbuf + br * 64 + ((ls ^ ((br >> 1) & 3)) << 4));
    }
#pragma unroll
    for (int i = 0; i < 4; i++)
#pragma unroll
      for (int j = 0; j < 4; j++)
        acc[i][j] = __builtin_amdgcn_mfma_f32_16x16x32_bf16(af[i], bfr[j], acc[i][j], 0, 0, 0);
    __syncthreads();
  }
#pragma unroll
  for (int i = 0; i < 4; i++) {
#pragma unroll
    for (int r = 0; r < 4; r++) {
      int m = wr + i * 16 + ls * 4 + r;
      if (m < valid) {
        size_t base = (size_t)(rowStart + m) * DFF + n0 + wc;  // FIX: + wc
#pragma unroll
        for (int j = 0; j < 4; j++) {
          h[base + j * 16 + l15] = f2b(gelu_tanh(acc[i][j][r]));
        }
      }
    }
  }
}

// ---------------- FFN2: y += gate * (h @ W2_e), atomicAdd combine ----------------
__global__ __launch_bounds__(256) void ffn2_kernel(
    const unsigned short* __restrict__ h, const unsigned short* __restrict__ w2t,
    const int* __restrict__ tokList, const float* __restrict__ gateList,
    const int4* __restrict__ desc, const int* __restrict__ nTiles,
    float* __restrict__ y) {
  if ((int)blockIdx.x >= *nTiles) return;
  int4 d = desc[blockIdx.x];
  const int e = d.x, rowStart = d.y, valid = d.z;
  const int n0 = blockIdx.y * 128;

  __shared__ __align__(16) unsigned short Abuf[128 * 32];
  __shared__ __align__(16) unsigned short Bbuf[128 * 32];

  const int tid = threadIdx.x;
  const int lane = tid & 63;
  const int w = tid >> 6;

  const int r0 = w * 16 + (lane >> 2);
  const int r1 = r0 + 64;
  const int sp = lane & 3;
  const int k0s = (sp ^ ((r0 >> 1) & 3)) * 8;
  const int k1s = (sp ^ ((r1 >> 1) & 3)) * 8;

  const unsigned short* ga0 = h + (size_t)(rowStart + r0) * DFF + k0s;
  const unsigned short* ga1 = h + (size_t)(rowStart + r1) * DFF + k1s;
  const unsigned short* gb0 = w2t + ((size_t)e * DM + n0 + r0) * DFF + k0s;
  const unsigned short* gb1 = w2t + ((size_t)e * DM + n0 + r1) * DFF + k1s;

  char* la0 = (char*)Abuf + w * 1024;
  char* la1 = (char*)Abuf + 4096 + w * 1024;
  char* lb0 = (char*)Bbuf + w * 1024;
  char* lb1 = (char*)Bbuf + 4096 + w * 1024;

  const int wr = (w >> 1) * 64, wc = (w & 1) * 64;
  const int l15 = lane & 15, ls = lane >> 4;

  f32x4 zero = {0.f, 0.f, 0.f, 0.f};
  f32x4 acc[4][4];
#pragma unroll
  for (int i = 0; i < 4; i++)
#pragma unroll
    for (int j = 0; j < 4; j++) acc[i][j] = zero;

  for (int kt = 0; kt < DFF; kt += 32) {
    async16(ga0 + kt, la0);
    async16(ga1 + kt, la1);
    async16(gb0 + kt, lb0);
    async16(gb1 + kt, lb1);
    __syncthreads();
    bf16x8 af[4], bfr[4];
#pragma unroll
    for (int i = 0; i < 4; i++) {
      int ar = wr + i * 16 + l15;
      af[i] = *(const bf16x8*)((const char*)Abuf + ar * 64 + ((ls ^ ((ar >> 1) & 3)) << 4));
    }
#pragma unroll
    for (int j = 0; j < 4; j++) {
      int br = wc + j * 16 + l15;
      bfr[j] = *(const bf16x8*)((const char*)Bbuf + br * 64 + ((ls ^ ((br >> 1) & 3)) << 4));
    }
#pragma unroll
    for (int i = 0; i < 4; i++)
#pragma unroll
      for (int j = 0; j < 4; j++)
        acc[i][j] = __builtin_amdgcn_mfma_f32_16x16x32_bf16(af[i], bfr[j], acc[i][j], 0, 0, 0);
    __syncthreads();
  }
#pragma unroll
  for (int i = 0; i < 4; i++) {
#pragma unroll
    for (int r = 0; r < 4; r++) {
      int m = wr + i * 16 + ls * 4 + r;
      if (m < valid) {
        int row = rowStart + m;
        int tok = tokList[row] & (T_TOK - 1);
        float g = gateList[row];
        float* yr = y + (size_t)tok * DM + n0 + wc;  // FIX: + wc
#pragma unroll
        for (int j = 0; j < 4; j++) {
          atomicAdd(&yr[j * 16 + l15], g * acc[i][j][r]);
        }
      }
    }
  }
}

// ---------------- host launch ----------------
extern "C" void kernel_launch(void* const* d_in, const int* in_sizes, int n_in,
                              void* d_out, int out_size, void* d_ws, size_t ws_size,
                              hipStream_t stream) {
  const float* x   = (const float*)d_in[0];
  const float* Wg1 = (const float*)d_in[1];
  const float* bg1 = (const float*)d_in[2];
  const float* Wg2 = (const float*)d_in[3];
  const float* W1  = (const float*)d_in[4];
  const float* W2  = (const float*)d_in[5];
  float* y = (float*)d_out;
  char* ws = (char*)d_ws;

  const size_t SZ_W1T = (size_t)NE * DFF * DM * 2;
  const size_t OFF_W1T = 0;
  const size_t OFF_W2T = OFF_W1T + SZ_W1T;
  const size_t OFF_XB  = OFF_W2T + SZ_W1T;
  const size_t OFF_H   = OFF_XB + (size_t)T_TOK * DM * 2;
  const size_t OFF_TOK = OFF_H + (size_t)HROWS * DFF * 2;
  const size_t OFF_GATE = OFF_TOK + (size_t)HROWS * 4;
  const size_t OFF_TIDX = OFF_GATE + (size_t)HROWS * 4;
  const size_t OFF_TG   = OFF_TIDX + (size_t)2 * T_TOK * 4;
  const size_t OFF_META = OFF_TG + (size_t)2 * T_TOK * 4;
  const size_t NEED = OFF_META + 4096;

  hipMemsetAsync(d_out, 0, (size_t)out_size * 4, stream);
  if (ws_size < NEED) return;  // clean (zero) failure instead of OOB writes

  unsigned short* w1t = (unsigned short*)(ws + OFF_W1T);
  unsigned short* w2t = (unsigned short*)(ws + OFF_W2T);
  unsigned short* xb  = (unsigned short*)(ws + OFF_XB);
  unsigned short* h   = (unsigned short*)(ws + OFF_H);
  float* Ar           = (float*)(ws + OFF_H);  // overlay: dead before ffn1 writes h
  int* tokList        = (int*)(ws + OFF_TOK);
  float* gateList     = (float*)(ws + OFF_GATE);
  int* tIdx           = (int*)(ws + OFF_TIDX);
  float* tGate        = (float*)(ws + OFF_TG);
  int* counts         = (int*)(ws + OFF_META);
  int* fill           = (int*)(ws + OFF_META + 32);
  int* offsets        = (int*)(ws + OFF_META + 64);
  int* nTiles         = (int*)(ws + OFF_META + 128);
  int4* desc          = (int4*)(ws + OFF_META + 160);

  // zero token lists (+pad) and counts/fill
  hipMemsetAsync(ws + OFF_TOK, 0, (size_t)2 * HROWS * 4, stream);
  hipMemsetAsync(ws + OFF_META, 0, 64, stream);

  cast_x_kernel<<<dim3((T_TOK * DM / 4) / 256), dim3(256), 0, stream>>>(x, xb);
  transpose_cast_kernel<<<dim3(DFF / 32, DM / 32, NE), dim3(32, 8), 0, stream>>>(W1, w1t, DM, DFF);
  transpose_cast_kernel<<<dim3(DM / 32, DFF / 32, NE), dim3(32, 8), 0, stream>>>(W2, w2t, DFF, DM);

  router_gemm1_kernel<<<dim3(DM / 128, T_TOK / 128), dim3(256), 0, stream>>>(x, Wg1, bg1, Ar);
  router_topk_kernel<<<dim3(T_TOK / 4), dim3(256), 0, stream>>>(Ar, Wg2, tIdx, tGate, counts);
  build_tiles_kernel<<<dim3(1), dim3(64), 0, stream>>>(counts, offsets, desc, nTiles);
  scatter_kernel<<<dim3((2 * T_TOK) / 256), dim3(256), 0, stream>>>(tIdx, tGate, offsets, fill,
                                                                    tokList, gateList);

  ffn1_kernel<<<dim3(MAX_TILES, DFF / 128), dim3(256), 0, stream>>>(xb, w1t, tokList, desc,
                                                                    nTiles, h);
  ffn2_kernel<<<dim3(MAX_TILES, DM / 128), dim3(256), 0, stream>>>(h, w2t, tokList, gateList,
                                                                   desc, nTiles, y);
}

// Round 3
// 949.966 us; speedup vs baseline: 1.1520x; 1.1520x over previous
//
#include <hip/hip_runtime.h>
#include <hip/hip_bf16.h>
#include <math.h>

#define T_TOK 8192
#define DM 1024
#define DFF 4096
#define NE 8
#define HROWS 16512
#define MAX_TILES 136

typedef __attribute__((ext_vector_type(8))) short bf16x8;
typedef __attribute__((ext_vector_type(4))) float f32x4;

__device__ __forceinline__ void async16(const void* g, void* l) {
  __builtin_amdgcn_global_load_lds((const __attribute__((address_space(1))) void*)g,
                                   (__attribute__((address_space(3))) void*)l, 16, 0, 0);
}

__device__ __forceinline__ unsigned short f2b(float f) {
  __hip_bfloat16 h = __float2bfloat16(f);
  return *reinterpret_cast<unsigned short*>(&h);
}

__device__ __forceinline__ float tanh_fast(float z) {
  // 1 - 2/(e^{2z}+1); exact limits at +-inf, ~1e-7 rel error
  return 1.f - 2.f / (__expf(2.f * z) + 1.f);
}

__device__ __forceinline__ float gelu_fast(float v) {
  // 0.5v(1+tanh(c(v+0.044715 v^3))) == v*sigmoid(2c(v+0.044715v^3))
  float u = v + 0.044715f * v * v * v;
  return v / (1.f + __expf(-1.5957691216057308f * u));
}

// ---------------- cast x (fp32 -> bf16), 4 elems/thread ----------------
__global__ void cast_x_kernel(const float* __restrict__ in, unsigned short* __restrict__ out) {
  int i = blockIdx.x * blockDim.x + threadIdx.x;
  float4 v = reinterpret_cast<const float4*>(in)[i];
  ushort4 o;
  o.x = f2b(v.x); o.y = f2b(v.y); o.z = f2b(v.z); o.w = f2b(v.w);
  reinterpret_cast<ushort4*>(out)[i] = o;
}

// ---------------- transpose + cast: in fp32 [E][R][C] -> out bf16 [E][C][R] ----------------
__global__ void transpose_cast_kernel(const float* __restrict__ in, unsigned short* __restrict__ out,
                                      int R, int C) {
  __shared__ float tile[32][33];
  int e = blockIdx.z;
  int r0 = blockIdx.y * 32, c0 = blockIdx.x * 32;
  const float* src = in + (size_t)e * R * C;
  unsigned short* dst = out + (size_t)e * R * C;
  int tx = threadIdx.x, ty = threadIdx.y;  // (32,8)
#pragma unroll
  for (int i = 0; i < 32; i += 8) tile[ty + i][tx] = src[(size_t)(r0 + ty + i) * C + c0 + tx];
  __syncthreads();
#pragma unroll
  for (int i = 0; i < 32; i += 8) dst[(size_t)(c0 + ty + i) * R + r0 + tx] = f2b(tile[tx][ty + i]);
}

// ---------------- fused router: logits += tanh(X@Wg1+bg1)[:,n0:n0+128] @ Wg2[n0:n0+128,:]
__global__ __launch_bounds__(256) void router_fused_kernel(
    const float* __restrict__ X, const float* __restrict__ Wg1,
    const float* __restrict__ bg1, const float* __restrict__ Wg2,
    float* __restrict__ logits) {
  __shared__ float As[32][132];
  __shared__ float Bs[32][132];
  __shared__ float lgt[128 * NE];
  const int tid = threadIdx.x;
  const int m0 = blockIdx.y * 128, n0 = blockIdx.x * 128;
  const int tm = (tid & 15) * 8;
  const int tn = (tid >> 4) * 8;
  const int lm = tid >> 1;
  const int lk = (tid & 1) * 16;
  const int bk = (tid >> 4) * 2;
  const int bn = (tid & 15) * 8;

#pragma unroll
  for (int q = 0; q < 4; q++) lgt[tid * 4 + q] = 0.f;  // visible after first loop sync

  float acc[8][8] = {};
  const float* xrow = X + (size_t)(m0 + lm) * DM + lk;
  const float* br0 = Wg1 + (size_t)bk * DM + n0 + bn;
  const float* br1 = Wg1 + (size_t)(bk + 1) * DM + n0 + bn;
  for (int k0 = 0; k0 < DM; k0 += 32) {
    float4 a0 = *(const float4*)(xrow + k0);
    float4 a1 = *(const float4*)(xrow + k0 + 4);
    float4 a2 = *(const float4*)(xrow + k0 + 8);
    float4 a3 = *(const float4*)(xrow + k0 + 12);
    float4 b00 = *(const float4*)(br0 + (size_t)k0 * DM);
    float4 b01 = *(const float4*)(br0 + (size_t)k0 * DM + 4);
    float4 b10 = *(const float4*)(br1 + (size_t)k0 * DM);
    float4 b11 = *(const float4*)(br1 + (size_t)k0 * DM + 4);
    __syncthreads();
    As[lk + 0][lm] = a0.x;  As[lk + 1][lm] = a0.y;  As[lk + 2][lm] = a0.z;  As[lk + 3][lm] = a0.w;
    As[lk + 4][lm] = a1.x;  As[lk + 5][lm] = a1.y;  As[lk + 6][lm] = a1.z;  As[lk + 7][lm] = a1.w;
    As[lk + 8][lm] = a2.x;  As[lk + 9][lm] = a2.y;  As[lk + 10][lm] = a2.z; As[lk + 11][lm] = a2.w;
    As[lk + 12][lm] = a3.x; As[lk + 13][lm] = a3.y; As[lk + 14][lm] = a3.z; As[lk + 15][lm] = a3.w;
    *(float4*)&Bs[bk][bn] = b00;
    *(float4*)&Bs[bk][bn + 4] = b01;
    *(float4*)&Bs[bk + 1][bn] = b10;
    *(float4*)&Bs[bk + 1][bn + 4] = b11;
    __syncthreads();
#pragma unroll
    for (int k = 0; k < 32; k++) {
      float av[8], bv[8];
      *(float4*)&av[0] = *(const float4*)&As[k][tm];
      *(float4*)&av[4] = *(const float4*)&As[k][tm + 4];
      *(float4*)&bv[0] = *(const float4*)&Bs[k][tn];
      *(float4*)&bv[4] = *(const float4*)&Bs[k][tn + 4];
#pragma unroll
      for (int i = 0; i < 8; i++)
#pragma unroll
        for (int j = 0; j < 8; j++) acc[i][j] = fmaf(av[i], bv[j], acc[i][j]);
    }
  }
  // epilogue: tanh + partial logits into LDS, then one global atomic per slot
  float w2r[8][8];
#pragma unroll
  for (int j = 0; j < 8; j++) {
    float4 u = *(const float4*)(Wg2 + (size_t)(n0 + tn + j) * NE);
    float4 v = *(const float4*)(Wg2 + (size_t)(n0 + tn + j) * NE + 4);
    w2r[j][0] = u.x; w2r[j][1] = u.y; w2r[j][2] = u.z; w2r[j][3] = u.w;
    w2r[j][4] = v.x; w2r[j][5] = v.y; w2r[j][6] = v.z; w2r[j][7] = v.w;
  }
#pragma unroll
  for (int i = 0; i < 8; i++) {
    float hv[8];
#pragma unroll
    for (int j = 0; j < 8; j++) hv[j] = tanh_fast(acc[i][j] + bg1[n0 + tn + j]);
#pragma unroll
    for (int ee = 0; ee < NE; ee++) {
      float s = 0.f;
#pragma unroll
      for (int j = 0; j < 8; j++) s = fmaf(hv[j], w2r[j][ee], s);
      atomicAdd(&lgt[(tm + i) * NE + ee], s);
    }
  }
  __syncthreads();
#pragma unroll
  for (int q = 0; q < 4; q++) {
    int idx = tid * 4 + q;
    atomicAdd(&logits[(size_t)(m0 + (idx >> 3)) * NE + (idx & 7)], lgt[idx]);
  }
}

// ---------------- top-2 over 8 logits per token ----------------
__global__ __launch_bounds__(256) void topk_small_kernel(
    const float* __restrict__ logits, int* __restrict__ tIdx, float* __restrict__ tGate,
    int* __restrict__ counts) {
  __shared__ int lc[NE];
  const int tid = threadIdx.x;
  if (tid < NE) lc[tid] = 0;
  __syncthreads();
  int t = blockIdx.x * 256 + tid;
  float p[NE];
  float4 p0 = *(const float4*)(logits + (size_t)t * NE);
  float4 p1 = *(const float4*)(logits + (size_t)t * NE + 4);
  p[0] = p0.x; p[1] = p0.y; p[2] = p0.z; p[3] = p0.w;
  p[4] = p1.x; p[5] = p1.y; p[6] = p1.z; p[7] = p1.w;
  // top-2 on raw logits (exact compares; softmax is monotonic)
  float v1 = -1e30f, v2 = -1e30f; int i1 = 0, i2 = 1;
#pragma unroll
  for (int e = 0; e < NE; e++) {
    float v = p[e];
    if (v > v1) { v2 = v1; i2 = i1; v1 = v; i1 = e; }
    else if (v > v2) { v2 = v; i2 = e; }
  }
  float mx = v1;
  float s = 0.f;
#pragma unroll
  for (int e = 0; e < NE; e++) s += __expf(p[e] - mx);
  float inv = 1.f / s;
  float g1 = __expf(p[i1] - mx) * inv;
  float g2 = __expf(p[i2] - mx) * inv;
  float den = 1.f / (g1 + g2 + 1e-6f);
  tIdx[2 * t] = i1; tIdx[2 * t + 1] = i2;
  tGate[2 * t] = g1 * den; tGate[2 * t + 1] = g2 * den;
  atomicAdd(&lc[i1], 1);
  atomicAdd(&lc[i2], 1);
  __syncthreads();
  if (tid < NE) atomicAdd(&counts[tid], lc[tid]);
}

// ---------------- prefix sums + tile descriptors (single thread) ----------------
__global__ void build_tiles_kernel(const int* __restrict__ counts, int* __restrict__ offsets,
                                   int4* __restrict__ desc, int* __restrict__ nTiles) {
  if (threadIdx.x != 0 || blockIdx.x != 0) return;
  int off = 0, nt = 0;
  for (int e = 0; e < NE; e++) {
    offsets[e] = off;
    int c = counts[e];
    if (c < 0) c = 0;
    if (c > 2 * T_TOK) c = 2 * T_TOK;
    for (int r = 0; r < c && nt < MAX_TILES; r += 128) {
      int v = c - r; if (v > 128) v = 128;
      desc[nt++] = make_int4(e, off + r, v, 0);
    }
    off += c;
    if (off > 2 * T_TOK) off = 2 * T_TOK;
  }
  offsets[NE] = off;
  *nTiles = nt;
}

// ---------------- scatter tokens into expert-grouped lists ----------------
__global__ void scatter_kernel(const int* __restrict__ tIdx, const float* __restrict__ tGate,
                               const int* __restrict__ offsets, int* __restrict__ fill,
                               int* __restrict__ tokList, float* __restrict__ gateList) {
  int id = blockIdx.x * blockDim.x + threadIdx.x;
  if (id >= 2 * T_TOK) return;
  int e = tIdx[id] & 7;
  int pos = atomicAdd(&fill[e], 1);
  int row = offsets[e] + pos;
  if (row < 0 || row >= 2 * T_TOK) return;
  tokList[row] = id >> 1;
  gateList[row] = tGate[id];
}

// ---------------- FFN1: h = gelu(gather(xb) @ W1_e^T-layout), BK=64 ----------------
__global__ __launch_bounds__(256) void ffn1_kernel(
    const unsigned short* __restrict__ xb, const unsigned short* __restrict__ w1t,
    const int* __restrict__ tokList, const int4* __restrict__ desc,
    const int* __restrict__ nTiles, unsigned short* __restrict__ h) {
  if ((int)blockIdx.x >= *nTiles) return;
  int4 d = desc[blockIdx.x];
  const int e = d.x, rowStart = d.y, valid = d.z;
  const int n0 = blockIdx.y * 128;

  __shared__ __align__(16) unsigned short Abuf[128 * 64];  // 16 KB, 128B rows
  __shared__ __align__(16) unsigned short Bbuf[128 * 64];
  __shared__ int tIds[128];

  const int tid = threadIdx.x;
  const int lane = tid & 63;
  const int w = tid >> 6;

  if (tid < 128) tIds[tid] = tokList[rowStart + tid] & (T_TOK - 1);
  __syncthreads();

  // staging: wave w, issue i covers rows [i*32+w*8, +8); lane -> (row=lane>>3, chunk=lane&7)
  const int subrow = lane >> 3, c8 = lane & 7;
  const unsigned short* gA[4];
  const unsigned short* gB[4];
  char* lA[4];
  char* lB[4];
#pragma unroll
  for (int i = 0; i < 4; i++) {
    int r = i * 32 + w * 8 + subrow;
    int gc = (c8 ^ (r & 7)) * 8;  // pre-swizzled global source chunk
    gA[i] = xb + (size_t)tIds[r] * DM + gc;
    gB[i] = w1t + ((size_t)e * DFF + n0 + r) * DM + gc;
    lA[i] = (char*)Abuf + (i * 32 + w * 8) * 128;
    lB[i] = (char*)Bbuf + (i * 32 + w * 8) * 128;
  }

  const int wr = (w >> 1) * 64, wc = (w & 1) * 64;
  const int l15 = lane & 15, ls = lane >> 4;

  f32x4 zero = {0.f, 0.f, 0.f, 0.f};
  f32x4 acc[4][4];
#pragma unroll
  for (int i = 0; i < 4; i++)
#pragma unroll
    for (int j = 0; j < 4; j++) acc[i][j] = zero;

  for (int kt = 0; kt < DM; kt += 64) {
#pragma unroll
    for (int i = 0; i < 4; i++) async16(gA[i] + kt, lA[i]);
#pragma unroll
    for (int i = 0; i < 4; i++) async16(gB[i] + kt, lB[i]);
    __syncthreads();
#pragma unroll
    for (int kk = 0; kk < 2; kk++) {
      bf16x8 af[4], bfr[4];
#pragma unroll
      for (int i = 0; i < 4; i++) {
        int ar = wr + i * 16 + l15;
        int cc = (kk * 4 + ls) ^ (ar & 7);
        af[i] = *(const bf16x8*)((const char*)Abuf + ar * 128 + cc * 16);
      }
#pragma unroll
      for (int j = 0; j < 4; j++) {
        int br = wc + j * 16 + l15;
        int cc = (kk * 4 + ls) ^ (br & 7);
        bfr[j] = *(const bf16x8*)((const char*)Bbuf + br * 128 + cc * 16);
      }
#pragma unroll
      for (int i = 0; i < 4; i++)
#pragma unroll
        for (int j = 0; j < 4; j++)
          acc[i][j] = __builtin_amdgcn_mfma_f32_16x16x32_bf16(af[i], bfr[j], acc[i][j], 0, 0, 0);
    }
    __syncthreads();
  }
#pragma unroll
  for (int i = 0; i < 4; i++) {
#pragma unroll
    for (int r = 0; r < 4; r++) {
      int m = wr + i * 16 + ls * 4 + r;
      if (m < valid) {
        size_t base = (size_t)(rowStart + m) * DFF + n0 + wc;
#pragma unroll
        for (int j = 0; j < 4; j++) {
          h[base + j * 16 + l15] = f2b(gelu_fast(acc[i][j][r]));
        }
      }
    }
  }
}

// ---------------- FFN2: y += gate * (h @ W2_e^T-layout), BK=64, atomic combine ----------------
__global__ __launch_bounds__(256) void ffn2_kernel(
    const unsigned short* __restrict__ h, const unsigned short* __restrict__ w2t,
    const int* __restrict__ tokList, const float* __restrict__ gateList,
    const int4* __restrict__ desc, const int* __restrict__ nTiles,
    float* __restrict__ y) {
  if ((int)blockIdx.x >= *nTiles) return;
  int4 d = desc[blockIdx.x];
  const int e = d.x, rowStart = d.y, valid = d.z;
  const int n0 = blockIdx.y * 128;

  __shared__ __align__(16) unsigned short Abuf[128 * 64];
  __shared__ __align__(16) unsigned short Bbuf[128 * 64];

  const int tid = threadIdx.x;
  const int lane = tid & 63;
  const int w = tid >> 6;

  const int subrow = lane >> 3, c8 = lane & 7;
  const unsigned short* gA[4];
  const unsigned short* gB[4];
  char* lA[4];
  char* lB[4];
#pragma unroll
  for (int i = 0; i < 4; i++) {
    int r = i * 32 + w * 8 + subrow;
    int gc = (c8 ^ (r & 7)) * 8;
    gA[i] = h + (size_t)(rowStart + r) * DFF + gc;
    gB[i] = w2t + ((size_t)e * DM + n0 + r) * DFF + gc;
    lA[i] = (char*)Abuf + (i * 32 + w * 8) * 128;
    lB[i] = (char*)Bbuf + (i * 32 + w * 8) * 128;
  }

  const int wr = (w >> 1) * 64, wc = (w & 1) * 64;
  const int l15 = lane & 15, ls = lane >> 4;

  f32x4 zero = {0.f, 0.f, 0.f, 0.f};
  f32x4 acc[4][4];
#pragma unroll
  for (int i = 0; i < 4; i++)
#pragma unroll
    for (int j = 0; j < 4; j++) acc[i][j] = zero;

  for (int kt = 0; kt < DFF; kt += 64) {
#pragma unroll
    for (int i = 0; i < 4; i++) async16(gA[i] + kt, lA[i]);
#pragma unroll
    for (int i = 0; i < 4; i++) async16(gB[i] + kt, lB[i]);
    __syncthreads();
#pragma unroll
    for (int kk = 0; kk < 2; kk++) {
      bf16x8 af[4], bfr[4];
#pragma unroll
      for (int i = 0; i < 4; i++) {
        int ar = wr + i * 16 + l15;
        int cc = (kk * 4 + ls) ^ (ar & 7);
        af[i] = *(const bf16x8*)((const char*)Abuf + ar * 128 + cc * 16);
      }
#pragma unroll
      for (int j = 0; j < 4; j++) {
        int br = wc + j * 16 + l15;
        int cc = (kk * 4 + ls) ^ (br & 7);
        bfr[j] = *(const bf16x8*)((const char*)Bbuf + br * 128 + cc * 16);
      }
#pragma unroll
      for (int i = 0; i < 4; i++)
#pragma unroll
        for (int j = 0; j < 4; j++)
          acc[i][j] = __builtin_amdgcn_mfma_f32_16x16x32_bf16(af[i], bfr[j], acc[i][j], 0, 0, 0);
    }
    __syncthreads();
  }
#pragma unroll
  for (int i = 0; i < 4; i++) {
#pragma unroll
    for (int r = 0; r < 4; r++) {
      int m = wr + i * 16 + ls * 4 + r;
      if (m < valid) {
        int row = rowStart + m;
        int tok = tokList[row] & (T_TOK - 1);
        float g = gateList[row];
        float* yr = y + (size_t)tok * DM + n0 + wc;
#pragma unroll
        for (int j = 0; j < 4; j++) {
          atomicAdd(&yr[j * 16 + l15], g * acc[i][j][r]);
        }
      }
    }
  }
}

// ---------------- host launch ----------------
extern "C" void kernel_launch(void* const* d_in, const int* in_sizes, int n_in,
                              void* d_out, int out_size, void* d_ws, size_t ws_size,
                              hipStream_t stream) {
  const float* x   = (const float*)d_in[0];
  const float* Wg1 = (const float*)d_in[1];
  const float* bg1 = (const float*)d_in[2];
  const float* Wg2 = (const float*)d_in[3];
  const float* W1  = (const float*)d_in[4];
  const float* W2  = (const float*)d_in[5];
  float* y = (float*)d_out;
  char* ws = (char*)d_ws;

  const size_t SZ_W1T = (size_t)NE * DFF * DM * 2;
  const size_t OFF_W1T = 0;
  const size_t OFF_W2T = OFF_W1T + SZ_W1T;
  const size_t OFF_XB  = OFF_W2T + SZ_W1T;
  const size_t OFF_H   = OFF_XB + (size_t)T_TOK * DM * 2;
  const size_t OFF_TOK = OFF_H + (size_t)HROWS * DFF * 2;
  const size_t OFF_GATE = OFF_TOK + (size_t)HROWS * 4;
  const size_t OFF_TIDX = OFF_GATE + (size_t)HROWS * 4;
  const size_t OFF_TG   = OFF_TIDX + (size_t)2 * T_TOK * 4;
  const size_t OFF_LOG  = OFF_TG + (size_t)2 * T_TOK * 4;
  const size_t OFF_META = OFF_LOG + (size_t)T_TOK * NE * 4;
  const size_t NEED = OFF_META + 4096;

  hipMemsetAsync(d_out, 0, (size_t)out_size * 4, stream);
  if (ws_size < NEED) return;  // clean (zero) failure instead of OOB writes

  unsigned short* w1t = (unsigned short*)(ws + OFF_W1T);
  unsigned short* w2t = (unsigned short*)(ws + OFF_W2T);
  unsigned short* xb  = (unsigned short*)(ws + OFF_XB);
  unsigned short* h   = (unsigned short*)(ws + OFF_H);
  int* tokList        = (int*)(ws + OFF_TOK);
  float* gateList     = (float*)(ws + OFF_GATE);
  int* tIdx           = (int*)(ws + OFF_TIDX);
  float* tGate        = (float*)(ws + OFF_TG);
  float* logits       = (float*)(ws + OFF_LOG);
  int* counts         = (int*)(ws + OFF_META);
  int* fill           = (int*)(ws + OFF_META + 32);
  int* offsets        = (int*)(ws + OFF_META + 64);
  int* nTiles         = (int*)(ws + OFF_META + 128);
  int4* desc          = (int4*)(ws + OFF_META + 160);

  hipMemsetAsync(ws + OFF_TOK, 0, (size_t)2 * HROWS * 4, stream);
  hipMemsetAsync(ws + OFF_LOG, 0, (size_t)T_TOK * NE * 4, stream);
  hipMemsetAsync(ws + OFF_META, 0, 64, stream);

  cast_x_kernel<<<dim3((T_TOK * DM / 4) / 256), dim3(256), 0, stream>>>(x, xb);
  transpose_cast_kernel<<<dim3(DFF / 32, DM / 32, NE), dim3(32, 8), 0, stream>>>(W1, w1t, DM, DFF);
  transpose_cast_kernel<<<dim3(DM / 32, DFF / 32, NE), dim3(32, 8), 0, stream>>>(W2, w2t, DFF, DM);

  router_fused_kernel<<<dim3(DM / 128, T_TOK / 128), dim3(256), 0, stream>>>(x, Wg1, bg1, Wg2,
                                                                             logits);
  topk_small_kernel<<<dim3(T_TOK / 256), dim3(256), 0, stream>>>(logits, tIdx, tGate, counts);
  build_tiles_kernel<<<dim3(1), dim3(64), 0, stream>>>(counts, offsets, desc, nTiles);
  scatter_kernel<<<dim3((2 * T_TOK) / 256), dim3(256), 0, stream>>>(tIdx, tGate, offsets, fill,
                                                                    tokList, gateList);

  ffn1_kernel<<<dim3(MAX_TILES, DFF / 128), dim3(256), 0, stream>>>(xb, w1t, tokList, desc,
                                                                    nTiles, h);
  ffn2_kernel<<<dim3(MAX_TILES, DM / 128), dim3(256), 0, stream>>>(h, w2t, tokList, gateList,
                                                                   desc, nTiles, y);
}

// Round 4
// 895.087 us; speedup vs baseline: 1.2226x; 1.0613x over previous
//
#include <hip/hip_runtime.h>
#include <hip/hip_bf16.h>
#include <math.h>

#define T_TOK 8192
#define DM 1024
#define DFF 4096
#define NE 8
#define HROWS 16512
#define MAX_TILES 136

typedef __attribute__((ext_vector_type(8))) short bf16x8;
typedef __attribute__((ext_vector_type(4))) float f32x4;

__device__ __forceinline__ void async16(const void* g, void* l) {
  __builtin_amdgcn_global_load_lds((const __attribute__((address_space(1))) void*)g,
                                   (__attribute__((address_space(3))) void*)l, 16, 0, 0);
}

__device__ __forceinline__ unsigned short f2b(float f) {
  __hip_bfloat16 h = __float2bfloat16(f);
  return *reinterpret_cast<unsigned short*>(&h);
}

__device__ __forceinline__ float tanh_fast(float z) {
  return 1.f - 2.f / (__expf(2.f * z) + 1.f);
}

__device__ __forceinline__ float gelu_fast(float v) {
  float u = v + 0.044715f * v * v * v;
  return v / (1.f + __expf(-1.5957691216057308f * u));
}

// ---------------- cast x (fp32 -> bf16), 4 elems/thread ----------------
__global__ void cast_x_kernel(const float* __restrict__ in, unsigned short* __restrict__ out) {
  int i = blockIdx.x * blockDim.x + threadIdx.x;
  float4 v = reinterpret_cast<const float4*>(in)[i];
  ushort4 o;
  o.x = f2b(v.x); o.y = f2b(v.y); o.z = f2b(v.z); o.w = f2b(v.w);
  reinterpret_cast<ushort4*>(out)[i] = o;
}

// ---------------- transpose + cast: in fp32 [E][R][C] -> out bf16 [E][C][R] ----------------
__global__ void transpose_cast_kernel(const float* __restrict__ in, unsigned short* __restrict__ out,
                                      int R, int C) {
  __shared__ float tile[32][33];
  int e = blockIdx.z;
  int r0 = blockIdx.y * 32, c0 = blockIdx.x * 32;
  const float* src = in + (size_t)e * R * C;
  unsigned short* dst = out + (size_t)e * R * C;
  int tx = threadIdx.x, ty = threadIdx.y;  // (32,8)
#pragma unroll
  for (int i = 0; i < 32; i += 8) tile[ty + i][tx] = src[(size_t)(r0 + ty + i) * C + c0 + tx];
  __syncthreads();
#pragma unroll
  for (int i = 0; i < 32; i += 8) dst[(size_t)(c0 + ty + i) * R + r0 + tx] = f2b(tile[tx][ty + i]);
}

// ---------------- fused router: logits += tanh(X@Wg1+bg1)[:,n0:n0+128] @ Wg2[n0:n0+128,:]
__global__ __launch_bounds__(256) void router_fused_kernel(
    const float* __restrict__ X, const float* __restrict__ Wg1,
    const float* __restrict__ bg1, const float* __restrict__ Wg2,
    float* __restrict__ logits) {
  __shared__ float As[32][132];
  __shared__ float Bs[32][132];
  __shared__ float lgt[128 * NE];
  const int tid = threadIdx.x;
  const int m0 = blockIdx.y * 128, n0 = blockIdx.x * 128;
  const int tm = (tid & 15) * 8;
  const int tn = (tid >> 4) * 8;
  const int lm = tid >> 1;
  const int lk = (tid & 1) * 16;
  const int bk = (tid >> 4) * 2;
  const int bn = (tid & 15) * 8;

#pragma unroll
  for (int q = 0; q < 4; q++) lgt[tid * 4 + q] = 0.f;

  float acc[8][8] = {};
  const float* xrow = X + (size_t)(m0 + lm) * DM + lk;
  const float* br0 = Wg1 + (size_t)bk * DM + n0 + bn;
  const float* br1 = Wg1 + (size_t)(bk + 1) * DM + n0 + bn;
  for (int k0 = 0; k0 < DM; k0 += 32) {
    float4 a0 = *(const float4*)(xrow + k0);
    float4 a1 = *(const float4*)(xrow + k0 + 4);
    float4 a2 = *(const float4*)(xrow + k0 + 8);
    float4 a3 = *(const float4*)(xrow + k0 + 12);
    float4 b00 = *(const float4*)(br0 + (size_t)k0 * DM);
    float4 b01 = *(const float4*)(br0 + (size_t)k0 * DM + 4);
    float4 b10 = *(const float4*)(br1 + (size_t)k0 * DM);
    float4 b11 = *(const float4*)(br1 + (size_t)k0 * DM + 4);
    __syncthreads();
    As[lk + 0][lm] = a0.x;  As[lk + 1][lm] = a0.y;  As[lk + 2][lm] = a0.z;  As[lk + 3][lm] = a0.w;
    As[lk + 4][lm] = a1.x;  As[lk + 5][lm] = a1.y;  As[lk + 6][lm] = a1.z;  As[lk + 7][lm] = a1.w;
    As[lk + 8][lm] = a2.x;  As[lk + 9][lm] = a2.y;  As[lk + 10][lm] = a2.z; As[lk + 11][lm] = a2.w;
    As[lk + 12][lm] = a3.x; As[lk + 13][lm] = a3.y; As[lk + 14][lm] = a3.z; As[lk + 15][lm] = a3.w;
    *(float4*)&Bs[bk][bn] = b00;
    *(float4*)&Bs[bk][bn + 4] = b01;
    *(float4*)&Bs[bk + 1][bn] = b10;
    *(float4*)&Bs[bk + 1][bn + 4] = b11;
    __syncthreads();
#pragma unroll
    for (int k = 0; k < 32; k++) {
      float av[8], bv[8];
      *(float4*)&av[0] = *(const float4*)&As[k][tm];
      *(float4*)&av[4] = *(const float4*)&As[k][tm + 4];
      *(float4*)&bv[0] = *(const float4*)&Bs[k][tn];
      *(float4*)&bv[4] = *(const float4*)&Bs[k][tn + 4];
#pragma unroll
      for (int i = 0; i < 8; i++)
#pragma unroll
        for (int j = 0; j < 8; j++) acc[i][j] = fmaf(av[i], bv[j], acc[i][j]);
    }
  }
  float w2r[8][8];
#pragma unroll
  for (int j = 0; j < 8; j++) {
    float4 u = *(const float4*)(Wg2 + (size_t)(n0 + tn + j) * NE);
    float4 v = *(const float4*)(Wg2 + (size_t)(n0 + tn + j) * NE + 4);
    w2r[j][0] = u.x; w2r[j][1] = u.y; w2r[j][2] = u.z; w2r[j][3] = u.w;
    w2r[j][4] = v.x; w2r[j][5] = v.y; w2r[j][6] = v.z; w2r[j][7] = v.w;
  }
#pragma unroll
  for (int i = 0; i < 8; i++) {
    float hv[8];
#pragma unroll
    for (int j = 0; j < 8; j++) hv[j] = tanh_fast(acc[i][j] + bg1[n0 + tn + j]);
#pragma unroll
    for (int ee = 0; ee < NE; ee++) {
      float s = 0.f;
#pragma unroll
      for (int j = 0; j < 8; j++) s = fmaf(hv[j], w2r[j][ee], s);
      atomicAdd(&lgt[(tm + i) * NE + ee], s);
    }
  }
  __syncthreads();
#pragma unroll
  for (int q = 0; q < 4; q++) {
    int idx = tid * 4 + q;
    atomicAdd(&logits[(size_t)(m0 + (idx >> 3)) * NE + (idx & 7)], lgt[idx]);
  }
}

// ---------------- top-2 over 8 logits per token ----------------
__global__ __launch_bounds__(256) void topk_small_kernel(
    const float* __restrict__ logits, int* __restrict__ tIdx, float* __restrict__ tGate,
    int* __restrict__ counts) {
  __shared__ int lc[NE];
  const int tid = threadIdx.x;
  if (tid < NE) lc[tid] = 0;
  __syncthreads();
  int t = blockIdx.x * 256 + tid;
  float p[NE];
  float4 p0 = *(const float4*)(logits + (size_t)t * NE);
  float4 p1 = *(const float4*)(logits + (size_t)t * NE + 4);
  p[0] = p0.x; p[1] = p0.y; p[2] = p0.z; p[3] = p0.w;
  p[4] = p1.x; p[5] = p1.y; p[6] = p1.z; p[7] = p1.w;
  float v1 = -1e30f, v2 = -1e30f; int i1 = 0, i2 = 1;
#pragma unroll
  for (int e = 0; e < NE; e++) {
    float v = p[e];
    if (v > v1) { v2 = v1; i2 = i1; v1 = v; i1 = e; }
    else if (v > v2) { v2 = v; i2 = e; }
  }
  float mx = v1;
  float s = 0.f;
#pragma unroll
  for (int e = 0; e < NE; e++) s += __expf(p[e] - mx);
  float inv = 1.f / s;
  float g1 = __expf(p[i1] - mx) * inv;
  float g2 = __expf(p[i2] - mx) * inv;
  float den = 1.f / (g1 + g2 + 1e-6f);
  tIdx[2 * t] = i1; tIdx[2 * t + 1] = i2;
  tGate[2 * t] = g1 * den; tGate[2 * t + 1] = g2 * den;
  atomicAdd(&lc[i1], 1);
  atomicAdd(&lc[i2], 1);
  __syncthreads();
  if (tid < NE) atomicAdd(&counts[tid], lc[tid]);
}

// ---------------- prefix sums + tile descriptors (single thread) ----------------
__global__ void build_tiles_kernel(const int* __restrict__ counts, int* __restrict__ offsets,
                                   int4* __restrict__ desc, int* __restrict__ nTiles) {
  if (threadIdx.x != 0 || blockIdx.x != 0) return;
  int off = 0, nt = 0;
  for (int e = 0; e < NE; e++) {
    offsets[e] = off;
    int c = counts[e];
    if (c < 0) c = 0;
    if (c > 2 * T_TOK) c = 2 * T_TOK;
    for (int r = 0; r < c && nt < MAX_TILES; r += 128) {
      int v = c - r; if (v > 128) v = 128;
      desc[nt++] = make_int4(e, off + r, v, 0);
    }
    off += c;
    if (off > 2 * T_TOK) off = 2 * T_TOK;
  }
  offsets[NE] = off;
  *nTiles = nt;
}

// ---------------- scatter tokens into expert-grouped lists ----------------
__global__ void scatter_kernel(const int* __restrict__ tIdx, const float* __restrict__ tGate,
                               const int* __restrict__ offsets, int* __restrict__ fill,
                               int* __restrict__ tokList, float* __restrict__ gateList) {
  int id = blockIdx.x * blockDim.x + threadIdx.x;
  if (id >= 2 * T_TOK) return;
  int e = tIdx[id] & 7;
  int pos = atomicAdd(&fill[e], 1);
  int row = offsets[e] + pos;
  if (row < 0 || row >= 2 * T_TOK) return;
  tokList[row] = id >> 1;
  gateList[row] = tGate[id];
}

// ---------------- FFN1: h = gelu(gather(xb) @ W1_e), BK=32, 2-phase dbuf ----------------
__global__ __launch_bounds__(256) void ffn1_kernel(
    const unsigned short* __restrict__ xb, const unsigned short* __restrict__ w1t,
    const int* __restrict__ tokList, const int4* __restrict__ desc,
    const int* __restrict__ nTiles, unsigned short* __restrict__ h) {
  if ((int)blockIdx.y >= *nTiles) return;
  int4 d = desc[blockIdx.y];
  const int e = d.x, rowStart = d.y, valid = d.z;
  const int n0 = blockIdx.x * 128;

  // [buf][A|B][128 rows * 32 cols] bf16 ; per-buf stride 16384 B, B at +8192
  __shared__ __align__(16) char AB[2][16384];

  const int tid = threadIdx.x;
  const int lane = tid & 63;
  const int w = tid >> 6;

  // staging map (verified 2-way-free swizzle): row r0=w*16+(lane>>2), chunk sp^((r>>1)&3)
  const int r0 = w * 16 + (lane >> 2);
  const int r1 = r0 + 64;
  const int sp = lane & 3;
  const int k0s = (sp ^ ((r0 >> 1) & 3)) * 8;
  const int k1s = (sp ^ ((r1 >> 1) & 3)) * 8;

  const unsigned short* gA0 = xb + (size_t)(tokList[rowStart + r0] & (T_TOK - 1)) * DM + k0s;
  const unsigned short* gA1 = xb + (size_t)(tokList[rowStart + r1] & (T_TOK - 1)) * DM + k1s;
  const unsigned short* gB0 = w1t + ((size_t)e * DFF + n0 + r0) * DM + k0s;
  const unsigned short* gB1 = w1t + ((size_t)e * DFF + n0 + r1) * DM + k1s;

  const int wr = (w >> 1) * 64, wc = (w & 1) * 64;
  const int l15 = lane & 15, ls = lane >> 4;

  f32x4 zero = {0.f, 0.f, 0.f, 0.f};
  f32x4 acc[4][4];
#pragma unroll
  for (int i = 0; i < 4; i++)
#pragma unroll
    for (int j = 0; j < 4; j++) acc[i][j] = zero;

  auto stage = [&](int buf, int kt) {
    char* dA = &AB[buf][0] + w * 1024;
    char* dB = dA + 8192;
    async16(gA0 + kt, dA);
    async16(gA1 + kt, dA + 4096);
    async16(gB0 + kt, dB);
    async16(gB1 + kt, dB + 4096);
  };
  auto computeTile = [&](int cur) {
    const char* rA = &AB[cur][0];
    const char* rB = rA + 8192;
    bf16x8 af[4], bfv[4];
#pragma unroll
    for (int i = 0; i < 4; i++) {
      int ar = wr + i * 16 + l15;
      af[i] = *(const bf16x8*)(rA + ar * 64 + ((ls ^ ((ar >> 1) & 3)) << 4));
    }
#pragma unroll
    for (int j = 0; j < 4; j++) {
      int br = wc + j * 16 + l15;
      bfv[j] = *(const bf16x8*)(rB + br * 64 + ((ls ^ ((br >> 1) & 3)) << 4));
    }
#pragma unroll
    for (int i = 0; i < 4; i++)
#pragma unroll
      for (int j = 0; j < 4; j++)
        acc[i][j] = __builtin_amdgcn_mfma_f32_16x16x32_bf16(af[i], bfv[j], acc[i][j], 0, 0, 0);
  };

  const int NIT = DM / 32;
  stage(0, 0);
  __syncthreads();
#pragma unroll 2
  for (int t = 0; t < NIT - 1; t++) {
    const int cur = t & 1;
    stage(cur ^ 1, (t + 1) * 32);   // issue next-tile loads BEFORE compute
    computeTile(cur);               // MFMA hides the load latency
    __syncthreads();                // drains vmcnt+lgkmcnt after compute
  }
  computeTile((NIT - 1) & 1);

#pragma unroll
  for (int i = 0; i < 4; i++) {
#pragma unroll
    for (int r = 0; r < 4; r++) {
      int m = wr + i * 16 + ls * 4 + r;
      if (m < valid) {
        size_t base = (size_t)(rowStart + m) * DFF + n0 + wc;
#pragma unroll
        for (int j = 0; j < 4; j++) {
          h[base + j * 16 + l15] = f2b(gelu_fast(acc[i][j][r]));
        }
      }
    }
  }
}

// ---------------- FFN2: y += gate * (h @ W2_e), BK=32, 2-phase dbuf, atomic combine ----------------
__global__ __launch_bounds__(256) void ffn2_kernel(
    const unsigned short* __restrict__ h, const unsigned short* __restrict__ w2t,
    const int* __restrict__ tokList, const float* __restrict__ gateList,
    const int4* __restrict__ desc, const int* __restrict__ nTiles,
    float* __restrict__ y) {
  if ((int)blockIdx.y >= *nTiles) return;
  int4 d = desc[blockIdx.y];
  const int e = d.x, rowStart = d.y, valid = d.z;
  const int n0 = blockIdx.x * 128;

  __shared__ __align__(16) char AB[2][16384];

  const int tid = threadIdx.x;
  const int lane = tid & 63;
  const int w = tid >> 6;

  const int r0 = w * 16 + (lane >> 2);
  const int r1 = r0 + 64;
  const int sp = lane & 3;
  const int k0s = (sp ^ ((r0 >> 1) & 3)) * 8;
  const int k1s = (sp ^ ((r1 >> 1) & 3)) * 8;

  const unsigned short* gA0 = h + (size_t)(rowStart + r0) * DFF + k0s;
  const unsigned short* gA1 = h + (size_t)(rowStart + r1) * DFF + k1s;
  const unsigned short* gB0 = w2t + ((size_t)e * DM + n0 + r0) * DFF + k0s;
  const unsigned short* gB1 = w2t + ((size_t)e * DM + n0 + r1) * DFF + k1s;

  const int wr = (w >> 1) * 64, wc = (w & 1) * 64;
  const int l15 = lane & 15, ls = lane >> 4;

  f32x4 zero = {0.f, 0.f, 0.f, 0.f};
  f32x4 acc[4][4];
#pragma unroll
  for (int i = 0; i < 4; i++)
#pragma unroll
    for (int j = 0; j < 4; j++) acc[i][j] = zero;

  auto stage = [&](int buf, int kt) {
    char* dA = &AB[buf][0] + w * 1024;
    char* dB = dA + 8192;
    async16(gA0 + kt, dA);
    async16(gA1 + kt, dA + 4096);
    async16(gB0 + kt, dB);
    async16(gB1 + kt, dB + 4096);
  };
  auto computeTile = [&](int cur) {
    const char* rA = &AB[cur][0];
    const char* rB = rA + 8192;
    bf16x8 af[4], bfv[4];
#pragma unroll
    for (int i = 0; i < 4; i++) {
      int ar = wr + i * 16 + l15;
      af[i] = *(const bf16x8*)(rA + ar * 64 + ((ls ^ ((ar >> 1) & 3)) << 4));
    }
#pragma unroll
    for (int j = 0; j < 4; j++) {
      int br = wc + j * 16 + l15;
      bfv[j] = *(const bf16x8*)(rB + br * 64 + ((ls ^ ((br >> 1) & 3)) << 4));
    }
#pragma unroll
    for (int i = 0; i < 4; i++)
#pragma unroll
      for (int j = 0; j < 4; j++)
        acc[i][j] = __builtin_amdgcn_mfma_f32_16x16x32_bf16(af[i], bfv[j], acc[i][j], 0, 0, 0);
  };

  const int NIT = DFF / 32;
  stage(0, 0);
  __syncthreads();
#pragma unroll 2
  for (int t = 0; t < NIT - 1; t++) {
    const int cur = t & 1;
    stage(cur ^ 1, (t + 1) * 32);
    computeTile(cur);
    __syncthreads();
  }
  computeTile((NIT - 1) & 1);

#pragma unroll
  for (int i = 0; i < 4; i++) {
#pragma unroll
    for (int r = 0; r < 4; r++) {
      int m = wr + i * 16 + ls * 4 + r;
      if (m < valid) {
        int row = rowStart + m;
        int tok = tokList[row] & (T_TOK - 1);
        float g = gateList[row];
        float* yr = y + (size_t)tok * DM + n0 + wc;
#pragma unroll
        for (int j = 0; j < 4; j++) {
          atomicAdd(&yr[j * 16 + l15], g * acc[i][j][r]);
        }
      }
    }
  }
}

// ---------------- host launch ----------------
extern "C" void kernel_launch(void* const* d_in, const int* in_sizes, int n_in,
                              void* d_out, int out_size, void* d_ws, size_t ws_size,
                              hipStream_t stream) {
  const float* x   = (const float*)d_in[0];
  const float* Wg1 = (const float*)d_in[1];
  const float* bg1 = (const float*)d_in[2];
  const float* Wg2 = (const float*)d_in[3];
  const float* W1  = (const float*)d_in[4];
  const float* W2  = (const float*)d_in[5];
  float* y = (float*)d_out;
  char* ws = (char*)d_ws;

  const size_t SZ_W1T = (size_t)NE * DFF * DM * 2;
  const size_t OFF_W1T = 0;
  const size_t OFF_W2T = OFF_W1T + SZ_W1T;
  const size_t OFF_XB  = OFF_W2T + SZ_W1T;
  const size_t OFF_H   = OFF_XB + (size_t)T_TOK * DM * 2;
  const size_t OFF_TOK = OFF_H + (size_t)HROWS * DFF * 2;
  const size_t OFF_GATE = OFF_TOK + (size_t)HROWS * 4;
  const size_t OFF_TIDX = OFF_GATE + (size_t)HROWS * 4;
  const size_t OFF_TG   = OFF_TIDX + (size_t)2 * T_TOK * 4;
  const size_t OFF_LOG  = OFF_TG + (size_t)2 * T_TOK * 4;
  const size_t OFF_META = OFF_LOG + (size_t)T_TOK * NE * 4;
  const size_t NEED = OFF_META + 4096;

  hipMemsetAsync(d_out, 0, (size_t)out_size * 4, stream);
  if (ws_size < NEED) return;  // clean (zero) failure instead of OOB writes

  unsigned short* w1t = (unsigned short*)(ws + OFF_W1T);
  unsigned short* w2t = (unsigned short*)(ws + OFF_W2T);
  unsigned short* xb  = (unsigned short*)(ws + OFF_XB);
  unsigned short* h   = (unsigned short*)(ws + OFF_H);
  int* tokList        = (int*)(ws + OFF_TOK);
  float* gateList     = (float*)(ws + OFF_GATE);
  int* tIdx           = (int*)(ws + OFF_TIDX);
  float* tGate        = (float*)(ws + OFF_TG);
  float* logits       = (float*)(ws + OFF_LOG);
  int* counts         = (int*)(ws + OFF_META);
  int* fill           = (int*)(ws + OFF_META + 32);
  int* offsets        = (int*)(ws + OFF_META + 64);
  int* nTiles         = (int*)(ws + OFF_META + 128);
  int4* desc          = (int4*)(ws + OFF_META + 160);

  hipMemsetAsync(ws + OFF_TOK, 0, (size_t)2 * HROWS * 4, stream);
  hipMemsetAsync(ws + OFF_LOG, 0, (size_t)T_TOK * NE * 4, stream);
  hipMemsetAsync(ws + OFF_META, 0, 64, stream);

  cast_x_kernel<<<dim3((T_TOK * DM / 4) / 256), dim3(256), 0, stream>>>(x, xb);
  transpose_cast_kernel<<<dim3(DFF / 32, DM / 32, NE), dim3(32, 8), 0, stream>>>(W1, w1t, DM, DFF);
  transpose_cast_kernel<<<dim3(DM / 32, DFF / 32, NE), dim3(32, 8), 0, stream>>>(W2, w2t, DFF, DM);

  router_fused_kernel<<<dim3(DM / 128, T_TOK / 128), dim3(256), 0, stream>>>(x, Wg1, bg1, Wg2,
                                                                             logits);
  topk_small_kernel<<<dim3(T_TOK / 256), dim3(256), 0, stream>>>(logits, tIdx, tGate, counts);
  build_tiles_kernel<<<dim3(1), dim3(64), 0, stream>>>(counts, offsets, desc, nTiles);
  scatter_kernel<<<dim3((2 * T_TOK) / 256), dim3(256), 0, stream>>>(tIdx, tGate, offsets, fill,
                                                                    tokList, gateList);

  // tile index in blockIdx.y, N-block in blockIdx.x
  ffn1_kernel<<<dim3(DFF / 128, MAX_TILES), dim3(256), 0, stream>>>(xb, w1t, tokList, desc,
                                                                    nTiles, h);
  ffn2_kernel<<<dim3(DM / 128, MAX_TILES), dim3(256), 0, stream>>>(h, w2t, tokList, gateList,
                                                                   desc, nTiles, y);
}

// Round 6
// 804.600 us; speedup vs baseline: 1.3601x; 1.1125x over previous
//
#include <hip/hip_runtime.h>
#include <hip/hip_bf16.h>
#include <math.h>

#define T_TOK 8192
#define DM 1024
#define DFF 4096
#define NE 8
#define HROWS 16512
#define MAX_TILES 136

typedef __attribute__((ext_vector_type(8))) short bf16x8;
typedef __attribute__((ext_vector_type(4))) float f32x4;
typedef __attribute__((ext_vector_type(8))) _Float16 f16x8;
typedef __attribute__((ext_vector_type(4))) _Float16 f16x4;

__device__ __forceinline__ void async16(const void* g, void* l) {
  __builtin_amdgcn_global_load_lds((const __attribute__((address_space(1))) void*)g,
                                   (__attribute__((address_space(3))) void*)l, 16, 0, 0);
}

__device__ __forceinline__ unsigned short f2b(float f) {
  __hip_bfloat16 h = __float2bfloat16(f);
  return *reinterpret_cast<unsigned short*>(&h);
}

__device__ __forceinline__ float tanh_fast(float z) {
  return 1.f - 2.f / (__expf(2.f * z) + 1.f);
}

__device__ __forceinline__ float gelu_fast(float v) {
  float u = v + 0.044715f * v * v * v;
  return v / (1.f + __expf(-1.5957691216057308f * u));
}

// ---------------- split x: fp32 -> bf16 (for FFN) + f16 hi/lo (for router) ----------------
__global__ void split_x_kernel(const float* __restrict__ in, unsigned short* __restrict__ xb,
                               _Float16* __restrict__ xh, _Float16* __restrict__ xl) {
  int i = blockIdx.x * blockDim.x + threadIdx.x;
  float4 v = reinterpret_cast<const float4*>(in)[i];
  ushort4 ob;
  f16x4 oh, ol;
  float f, hf;
  f = v.x; oh[0] = (_Float16)f; hf = (float)oh[0]; ol[0] = (_Float16)((f - hf) * 2048.0f); ob.x = f2b(f);
  f = v.y; oh[1] = (_Float16)f; hf = (float)oh[1]; ol[1] = (_Float16)((f - hf) * 2048.0f); ob.y = f2b(f);
  f = v.z; oh[2] = (_Float16)f; hf = (float)oh[2]; ol[2] = (_Float16)((f - hf) * 2048.0f); ob.z = f2b(f);
  f = v.w; oh[3] = (_Float16)f; hf = (float)oh[3]; ol[3] = (_Float16)((f - hf) * 2048.0f); ob.w = f2b(f);
  reinterpret_cast<ushort4*>(xb)[i] = ob;
  reinterpret_cast<f16x4*>(xh)[i] = oh;
  reinterpret_cast<f16x4*>(xl)[i] = ol;
}

// ---------------- transpose + split Wg1: [k][n] fp32 -> [n][k] f16 hi/lo ----------------
__global__ void transpose_split_w_kernel(const float* __restrict__ in,
                                         _Float16* __restrict__ outh, _Float16* __restrict__ outl) {
  __shared__ float tile[32][33];
  int r0 = blockIdx.y * 32, c0 = blockIdx.x * 32;
  int tx = threadIdx.x, ty = threadIdx.y;  // (32,8)
#pragma unroll
  for (int i = 0; i < 32; i += 8) tile[ty + i][tx] = in[(size_t)(r0 + ty + i) * DM + c0 + tx];
  __syncthreads();
#pragma unroll
  for (int i = 0; i < 32; i += 8) {
    float f = tile[tx][ty + i];
    _Float16 h = (_Float16)f;
    size_t idx = (size_t)(c0 + ty + i) * DM + r0 + tx;
    outh[idx] = h;
    outl[idx] = (_Float16)((f - (float)h) * 2048.0f);
  }
}

// ---------------- transpose + cast: in fp32 [E][R][C] -> out bf16 [E][C][R] ----------------
__global__ void transpose_cast_kernel(const float* __restrict__ in, unsigned short* __restrict__ out,
                                      int R, int C) {
  __shared__ float tile[32][33];
  int e = blockIdx.z;
  int r0 = blockIdx.y * 32, c0 = blockIdx.x * 32;
  const float* src = in + (size_t)e * R * C;
  unsigned short* dst = out + (size_t)e * R * C;
  int tx = threadIdx.x, ty = threadIdx.y;  // (32,8)
#pragma unroll
  for (int i = 0; i < 32; i += 8) tile[ty + i][tx] = src[(size_t)(r0 + ty + i) * C + c0 + tx];
  __syncthreads();
#pragma unroll
  for (int i = 0; i < 32; i += 8) dst[(size_t)(c0 + ty + i) * R + r0 + tx] = f2b(tile[tx][ty + i]);
}

// ---------------- MFMA router: logits += tanh(X@Wg1+bg1)[:,n-slice] @ Wg2[n-slice,:] ----------------
// f16 split: X = xh + xl/2048, W = wh + wl/2048 (elementwise).
// acc_hh = xh@wh ; acc_c = xh@wl + xl@wh ; hidden = acc_hh + acc_c/2048 (xl@wl/2^22 dropped)
__global__ __launch_bounds__(256) void router_mfma_kernel(
    const _Float16* __restrict__ xh, const _Float16* __restrict__ xl,
    const _Float16* __restrict__ wth, const _Float16* __restrict__ wtl,
    const float* __restrict__ bg1, const float* __restrict__ Wg2,
    float* __restrict__ logits) {
  // per buf: Ah @0, Al @8192, Bh @16384, Bl @24576 (each 128 rows x 64B)
  __shared__ __align__(16) char AB[2][32768];
  // [m][half][e] : half = wc>>6 -> the two column-half waves write disjoint slots (race fix)
  __shared__ float lgt[128 * 2 * NE];

  const int tid = threadIdx.x;
  const int lane = tid & 63;
  const int w = tid >> 6;
  const int n0 = blockIdx.x * 128, m0 = blockIdx.y * 128;

  const int r0 = w * 16 + (lane >> 2);
  const int r1 = r0 + 64;
  const int sp = lane & 3;
  const int k0s = (sp ^ ((r0 >> 1) & 3)) * 8;
  const int k1s = (sp ^ ((r1 >> 1) & 3)) * 8;

  const _Float16* gAh0 = xh + (size_t)(m0 + r0) * DM + k0s;
  const _Float16* gAh1 = xh + (size_t)(m0 + r1) * DM + k1s;
  const _Float16* gAl0 = xl + (size_t)(m0 + r0) * DM + k0s;
  const _Float16* gAl1 = xl + (size_t)(m0 + r1) * DM + k1s;
  const _Float16* gBh0 = wth + (size_t)(n0 + r0) * DM + k0s;
  const _Float16* gBh1 = wth + (size_t)(n0 + r1) * DM + k1s;
  const _Float16* gBl0 = wtl + (size_t)(n0 + r0) * DM + k0s;
  const _Float16* gBl1 = wtl + (size_t)(n0 + r1) * DM + k1s;

  const int wr = (w >> 1) * 64, wc = (w & 1) * 64;
  const int l15 = lane & 15, ls = lane >> 4;

  f32x4 zero = {0.f, 0.f, 0.f, 0.f};
  f32x4 acc_hh[4][4], acc_c[4][4];
#pragma unroll
  for (int i = 0; i < 4; i++)
#pragma unroll
    for (int j = 0; j < 4; j++) { acc_hh[i][j] = zero; acc_c[i][j] = zero; }

  auto stage = [&](int buf, int kt) {
    char* b = &AB[buf][0] + w * 1024;
    async16(gAh0 + kt, b);
    async16(gAh1 + kt, b + 4096);
    async16(gAl0 + kt, b + 8192);
    async16(gAl1 + kt, b + 8192 + 4096);
    async16(gBh0 + kt, b + 16384);
    async16(gBh1 + kt, b + 16384 + 4096);
    async16(gBl0 + kt, b + 24576);
    async16(gBl1 + kt, b + 24576 + 4096);
  };
  auto computeTile = [&](int cur) {
    const char* base = &AB[cur][0];
    f16x8 ah[4], bh[4], tmp[4];
#pragma unroll
    for (int i = 0; i < 4; i++) {
      int ar = wr + i * 16 + l15;
      ah[i] = *(const f16x8*)(base + ar * 64 + ((ls ^ ((ar >> 1) & 3)) << 4));
    }
#pragma unroll
    for (int j = 0; j < 4; j++) {
      int br = wc + j * 16 + l15;
      bh[j] = *(const f16x8*)(base + 16384 + br * 64 + ((ls ^ ((br >> 1) & 3)) << 4));
    }
#pragma unroll
    for (int i = 0; i < 4; i++)
#pragma unroll
      for (int j = 0; j < 4; j++)
        acc_hh[i][j] = __builtin_amdgcn_mfma_f32_16x16x32_f16(ah[i], bh[j], acc_hh[i][j], 0, 0, 0);
    // bl -> acc_c (reuse ah)
#pragma unroll
    for (int j = 0; j < 4; j++) {
      int br = wc + j * 16 + l15;
      tmp[j] = *(const f16x8*)(base + 24576 + br * 64 + ((ls ^ ((br >> 1) & 3)) << 4));
    }
#pragma unroll
    for (int i = 0; i < 4; i++)
#pragma unroll
      for (int j = 0; j < 4; j++)
        acc_c[i][j] = __builtin_amdgcn_mfma_f32_16x16x32_f16(ah[i], tmp[j], acc_c[i][j], 0, 0, 0);
    // al -> acc_c (reuse bh)
#pragma unroll
    for (int i = 0; i < 4; i++) {
      int ar = wr + i * 16 + l15;
      tmp[i] = *(const f16x8*)(base + 8192 + ar * 64 + ((ls ^ ((ar >> 1) & 3)) << 4));
    }
#pragma unroll
    for (int i = 0; i < 4; i++)
#pragma unroll
      for (int j = 0; j < 4; j++)
        acc_c[i][j] = __builtin_amdgcn_mfma_f32_16x16x32_f16(tmp[i], bh[j], acc_c[i][j], 0, 0, 0);
  };

  const int NIT = DM / 32;
  stage(0, 0);
  __syncthreads();
#pragma unroll 2
  for (int t = 0; t < NIT - 1; t++) {
    const int cur = t & 1;
    stage(cur ^ 1, (t + 1) * 32);
    computeTile(cur);
    __syncthreads();
  }
  computeTile((NIT - 1) & 1);

  // epilogue: hidden -> tanh -> partial logits; shuffle reduce-scatter over 16-lane group
  float w2r[4][8];
  float bias[4];
#pragma unroll
  for (int j = 0; j < 4; j++) {
    int gn = n0 + wc + j * 16 + l15;
    bias[j] = bg1[gn];
    float4 u = *(const float4*)(Wg2 + (size_t)gn * NE);
    float4 v = *(const float4*)(Wg2 + (size_t)gn * NE + 4);
    w2r[j][0] = u.x; w2r[j][1] = u.y; w2r[j][2] = u.z; w2r[j][3] = u.w;
    w2r[j][4] = v.x; w2r[j][5] = v.y; w2r[j][6] = v.z; w2r[j][7] = v.w;
  }
  const float inv2k = 1.0f / 2048.0f;
  const int half = wc >> 6;
  const bool b3 = (l15 & 8) != 0, b2 = (l15 & 4) != 0, b1 = (l15 & 2) != 0;
#pragma unroll
  for (int i = 0; i < 4; i++) {
#pragma unroll
    for (int r = 0; r < 4; r++) {
      float s[8] = {0.f, 0.f, 0.f, 0.f, 0.f, 0.f, 0.f, 0.f};
#pragma unroll
      for (int j = 0; j < 4; j++) {
        float hv = tanh_fast(acc_hh[i][j][r] + acc_c[i][j][r] * inv2k + bias[j]);
#pragma unroll
        for (int e = 0; e < NE; e++) s[e] = fmaf(hv, w2r[j][e], s[e]);
      }
      // reduce-scatter butterfly: expert e total lands in lanes with l15>>1 == e
      float t4_[4], t2_[2], t1_;
#pragma unroll
      for (int q = 0; q < 4; q++) {
        float snd = b3 ? s[q] : s[q + 4];
        float rcv = __shfl_xor(snd, 8);
        t4_[q] = (b3 ? s[q + 4] : s[q]) + rcv;
      }
#pragma unroll
      for (int q = 0; q < 2; q++) {
        float snd = b2 ? t4_[q] : t4_[q + 2];
        float rcv = __shfl_xor(snd, 4);
        t2_[q] = (b2 ? t4_[q + 2] : t4_[q]) + rcv;
      }
      {
        float snd = b1 ? t2_[0] : t2_[1];
        float rcv = __shfl_xor(snd, 2);
        t1_ = (b1 ? t2_[1] : t2_[0]) + rcv;
      }
      t1_ += __shfl_xor(t1_, 1);
      int m = wr + i * 16 + ls * 4 + r;
      if (!(l15 & 1)) lgt[m * (2 * NE) + half * NE + (l15 >> 1)] = t1_;  // race-free: unique (m,half,e)
    }
  }
  __syncthreads();
#pragma unroll
  for (int q = 0; q < 4; q++) {
    int idx = tid * 4 + q;                    // idx over 128*8 (m,e) pairs
    int m = idx >> 3, e = idx & 7;
    float v = lgt[m * (2 * NE) + e] + lgt[m * (2 * NE) + NE + e];
    atomicAdd(&logits[(size_t)(m0 + m) * NE + e], v);
  }
}

// ---------------- top-2 over 8 logits per token ----------------
__global__ __launch_bounds__(256) void topk_small_kernel(
    const float* __restrict__ logits, int* __restrict__ tIdx, float* __restrict__ tGate,
    int* __restrict__ counts) {
  __shared__ int lc[NE];
  const int tid = threadIdx.x;
  if (tid < NE) lc[tid] = 0;
  __syncthreads();
  int t = blockIdx.x * 256 + tid;
  float p[NE];
  float4 p0 = *(const float4*)(logits + (size_t)t * NE);
  float4 p1 = *(const float4*)(logits + (size_t)t * NE + 4);
  p[0] = p0.x; p[1] = p0.y; p[2] = p0.z; p[3] = p0.w;
  p[4] = p1.x; p[5] = p1.y; p[6] = p1.z; p[7] = p1.w;
  float v1 = -1e30f, v2 = -1e30f; int i1 = 0, i2 = 1;
#pragma unroll
  for (int e = 0; e < NE; e++) {
    float v = p[e];
    if (v > v1) { v2 = v1; i2 = i1; v1 = v; i1 = e; }
    else if (v > v2) { v2 = v; i2 = e; }
  }
  float mx = v1;
  float s = 0.f;
#pragma unroll
  for (int e = 0; e < NE; e++) s += __expf(p[e] - mx);
  float inv = 1.f / s;
  float g1 = __expf(p[i1] - mx) * inv;
  float g2 = __expf(p[i2] - mx) * inv;
  float den = 1.f / (g1 + g2 + 1e-6f);
  tIdx[2 * t] = i1; tIdx[2 * t + 1] = i2;
  tGate[2 * t] = g1 * den; tGate[2 * t + 1] = g2 * den;
  atomicAdd(&lc[i1], 1);
  atomicAdd(&lc[i2], 1);
  __syncthreads();
  if (tid < NE) atomicAdd(&counts[tid], lc[tid]);
}

// ---------------- prefix sums + tile descriptors (single thread) ----------------
__global__ void build_tiles_kernel(const int* __restrict__ counts, int* __restrict__ offsets,
                                   int4* __restrict__ desc, int* __restrict__ nTiles) {
  if (threadIdx.x != 0 || blockIdx.x != 0) return;
  int off = 0, nt = 0;
  for (int e = 0; e < NE; e++) {
    offsets[e] = off;
    int c = counts[e];
    if (c < 0) c = 0;
    if (c > 2 * T_TOK) c = 2 * T_TOK;
    for (int r = 0; r < c && nt < MAX_TILES; r += 128) {
      int v = c - r; if (v > 128) v = 128;
      desc[nt++] = make_int4(e, off + r, v, 0);
    }
    off += c;
    if (off > 2 * T_TOK) off = 2 * T_TOK;
  }
  offsets[NE] = off;
  *nTiles = nt;
}

// ---------------- scatter tokens into expert-grouped lists ----------------
__global__ void scatter_kernel(const int* __restrict__ tIdx, const float* __restrict__ tGate,
                               const int* __restrict__ offsets, int* __restrict__ fill,
                               int* __restrict__ tokList, float* __restrict__ gateList) {
  int id = blockIdx.x * blockDim.x + threadIdx.x;
  if (id >= 2 * T_TOK) return;
  int e = tIdx[id] & 7;
  int pos = atomicAdd(&fill[e], 1);
  int row = offsets[e] + pos;
  if (row < 0 || row >= 2 * T_TOK) return;
  tokList[row] = id >> 1;
  gateList[row] = tGate[id];
}

// ---------------- FFN1: h = gelu(gather(xb) @ W1_e), BK=32, 2-phase dbuf ----------------
__global__ __launch_bounds__(256) void ffn1_kernel(
    const unsigned short* __restrict__ xb, const unsigned short* __restrict__ w1t,
    const int* __restrict__ tokList, const int4* __restrict__ desc,
    const int* __restrict__ nTiles, unsigned short* __restrict__ h) {
  if ((int)blockIdx.y >= *nTiles) return;
  int4 d = desc[blockIdx.y];
  const int e = d.x, rowStart = d.y, valid = d.z;
  const int n0 = blockIdx.x * 128;

  __shared__ __align__(16) char AB[2][16384];

  const int tid = threadIdx.x;
  const int lane = tid & 63;
  const int w = tid >> 6;

  const int r0 = w * 16 + (lane >> 2);
  const int r1 = r0 + 64;
  const int sp = lane & 3;
  const int k0s = (sp ^ ((r0 >> 1) & 3)) * 8;
  const int k1s = (sp ^ ((r1 >> 1) & 3)) * 8;

  const unsigned short* gA0 = xb + (size_t)(tokList[rowStart + r0] & (T_TOK - 1)) * DM + k0s;
  const unsigned short* gA1 = xb + (size_t)(tokList[rowStart + r1] & (T_TOK - 1)) * DM + k1s;
  const unsigned short* gB0 = w1t + ((size_t)e * DFF + n0 + r0) * DM + k0s;
  const unsigned short* gB1 = w1t + ((size_t)e * DFF + n0 + r1) * DM + k1s;

  const int wr = (w >> 1) * 64, wc = (w & 1) * 64;
  const int l15 = lane & 15, ls = lane >> 4;

  f32x4 zero = {0.f, 0.f, 0.f, 0.f};
  f32x4 acc[4][4];
#pragma unroll
  for (int i = 0; i < 4; i++)
#pragma unroll
    for (int j = 0; j < 4; j++) acc[i][j] = zero;

  auto stage = [&](int buf, int kt) {
    char* dA = &AB[buf][0] + w * 1024;
    char* dB = dA + 8192;
    async16(gA0 + kt, dA);
    async16(gA1 + kt, dA + 4096);
    async16(gB0 + kt, dB);
    async16(gB1 + kt, dB + 4096);
  };
  auto computeTile = [&](int cur) {
    const char* rA = &AB[cur][0];
    const char* rB = rA + 8192;
    bf16x8 af[4], bfv[4];
#pragma unroll
    for (int i = 0; i < 4; i++) {
      int ar = wr + i * 16 + l15;
      af[i] = *(const bf16x8*)(rA + ar * 64 + ((ls ^ ((ar >> 1) & 3)) << 4));
    }
#pragma unroll
    for (int j = 0; j < 4; j++) {
      int br = wc + j * 16 + l15;
      bfv[j] = *(const bf16x8*)(rB + br * 64 + ((ls ^ ((br >> 1) & 3)) << 4));
    }
#pragma unroll
    for (int i = 0; i < 4; i++)
#pragma unroll
      for (int j = 0; j < 4; j++)
        acc[i][j] = __builtin_amdgcn_mfma_f32_16x16x32_bf16(af[i], bfv[j], acc[i][j], 0, 0, 0);
  };

  const int NIT = DM / 32;
  stage(0, 0);
  __syncthreads();
#pragma unroll 2
  for (int t = 0; t < NIT - 1; t++) {
    const int cur = t & 1;
    stage(cur ^ 1, (t + 1) * 32);
    computeTile(cur);
    __syncthreads();
  }
  computeTile((NIT - 1) & 1);

#pragma unroll
  for (int i = 0; i < 4; i++) {
#pragma unroll
    for (int r = 0; r < 4; r++) {
      int m = wr + i * 16 + ls * 4 + r;
      if (m < valid) {
        size_t base = (size_t)(rowStart + m) * DFF + n0 + wc;
#pragma unroll
        for (int j = 0; j < 4; j++) {
          h[base + j * 16 + l15] = f2b(gelu_fast(acc[i][j][r]));
        }
      }
    }
  }
}

// ---------------- FFN2: y += gate * (h @ W2_e), BK=32, 2-phase dbuf, atomic combine ----------------
__global__ __launch_bounds__(256) void ffn2_kernel(
    const unsigned short* __restrict__ h, const unsigned short* __restrict__ w2t,
    const int* __restrict__ tokList, const float* __restrict__ gateList,
    const int4* __restrict__ desc, const int* __restrict__ nTiles,
    float* __restrict__ y) {
  if ((int)blockIdx.y >= *nTiles) return;
  int4 d = desc[blockIdx.y];
  const int e = d.x, rowStart = d.y, valid = d.z;
  const int n0 = blockIdx.x * 128;

  __shared__ __align__(16) char AB[2][16384];

  const int tid = threadIdx.x;
  const int lane = tid & 63;
  const int w = tid >> 6;

  const int r0 = w * 16 + (lane >> 2);
  const int r1 = r0 + 64;
  const int sp = lane & 3;
  const int k0s = (sp ^ ((r0 >> 1) & 3)) * 8;
  const int k1s = (sp ^ ((r1 >> 1) & 3)) * 8;

  const unsigned short* gA0 = h + (size_t)(rowStart + r0) * DFF + k0s;
  const unsigned short* gA1 = h + (size_t)(rowStart + r1) * DFF + k1s;
  const unsigned short* gB0 = w2t + ((size_t)e * DM + n0 + r0) * DFF + k0s;
  const unsigned short* gB1 = w2t + ((size_t)e * DM + n0 + r1) * DFF + k1s;

  const int wr = (w >> 1) * 64, wc = (w & 1) * 64;
  const int l15 = lane & 15, ls = lane >> 4;

  f32x4 zero = {0.f, 0.f, 0.f, 0.f};
  f32x4 acc[4][4];
#pragma unroll
  for (int i = 0; i < 4; i++)
#pragma unroll
    for (int j = 0; j < 4; j++) acc[i][j] = zero;

  auto stage = [&](int buf, int kt) {
    char* dA = &AB[buf][0] + w * 1024;
    char* dB = dA + 8192;
    async16(gA0 + kt, dA);
    async16(gA1 + kt, dA + 4096);
    async16(gB0 + kt, dB);
    async16(gB1 + kt, dB + 4096);
  };
  auto computeTile = [&](int cur) {
    const char* rA = &AB[cur][0];
    const char* rB = rA + 8192;
    bf16x8 af[4], bfv[4];
#pragma unroll
    for (int i = 0; i < 4; i++) {
      int ar = wr + i * 16 + l15;
      af[i] = *(const bf16x8*)(rA + ar * 64 + ((ls ^ ((ar >> 1) & 3)) << 4));
    }
#pragma unroll
    for (int j = 0; j < 4; j++) {
      int br = wc + j * 16 + l15;
      bfv[j] = *(const bf16x8*)(rB + br * 64 + ((ls ^ ((br >> 1) & 3)) << 4));
    }
#pragma unroll
    for (int i = 0; i < 4; i++)
#pragma unroll
      for (int j = 0; j < 4; j++)
        acc[i][j] = __builtin_amdgcn_mfma_f32_16x16x32_bf16(af[i], bfv[j], acc[i][j], 0, 0, 0);
  };

  const int NIT = DFF / 32;
  stage(0, 0);
  __syncthreads();
#pragma unroll 2
  for (int t = 0; t < NIT - 1; t++) {
    const int cur = t & 1;
    stage(cur ^ 1, (t + 1) * 32);
    computeTile(cur);
    __syncthreads();
  }
  computeTile((NIT - 1) & 1);

#pragma unroll
  for (int i = 0; i < 4; i++) {
#pragma unroll
    for (int r = 0; r < 4; r++) {
      int m = wr + i * 16 + ls * 4 + r;
      if (m < valid) {
        int row = rowStart + m;
        int tok = tokList[row] & (T_TOK - 1);
        float g = gateList[row];
        float* yr = y + (size_t)tok * DM + n0 + wc;
#pragma unroll
        for (int j = 0; j < 4; j++) {
          atomicAdd(&yr[j * 16 + l15], g * acc[i][j][r]);
        }
      }
    }
  }
}

// ---------------- host launch ----------------
extern "C" void kernel_launch(void* const* d_in, const int* in_sizes, int n_in,
                              void* d_out, int out_size, void* d_ws, size_t ws_size,
                              hipStream_t stream) {
  const float* x   = (const float*)d_in[0];
  const float* Wg1 = (const float*)d_in[1];
  const float* bg1 = (const float*)d_in[2];
  const float* Wg2 = (const float*)d_in[3];
  const float* W1  = (const float*)d_in[4];
  const float* W2  = (const float*)d_in[5];
  float* y = (float*)d_out;
  char* ws = (char*)d_ws;

  const size_t SZ_W1T = (size_t)NE * DFF * DM * 2;
  const size_t OFF_W1T = 0;
  const size_t OFF_W2T = OFF_W1T + SZ_W1T;
  const size_t OFF_XB  = OFF_W2T + SZ_W1T;
  const size_t OFF_H   = OFF_XB + (size_t)T_TOK * DM * 2;
  const size_t OFF_TOK = OFF_H + (size_t)HROWS * DFF * 2;
  const size_t OFF_GATE = OFF_TOK + (size_t)HROWS * 4;
  const size_t OFF_TIDX = OFF_GATE + (size_t)HROWS * 4;
  const size_t OFF_TG   = OFF_TIDX + (size_t)2 * T_TOK * 4;
  const size_t OFF_LOG  = OFF_TG + (size_t)2 * T_TOK * 4;
  const size_t OFF_META = OFF_LOG + (size_t)T_TOK * NE * 4;
  const size_t NEED = OFF_META + 4096;

  // router split tensors overlay the (currently dead) h region
  const size_t OFF_XH  = OFF_H;                                  // 16 MB
  const size_t OFF_XL  = OFF_XH + (size_t)T_TOK * DM * 2;        // 16 MB
  const size_t OFF_WTH = OFF_XL + (size_t)T_TOK * DM * 2;        // 2 MB
  const size_t OFF_WTL = OFF_WTH + (size_t)DM * DM * 2;          // 2 MB

  hipMemsetAsync(d_out, 0, (size_t)out_size * 4, stream);
  if (ws_size < NEED) return;  // clean (zero) failure instead of OOB writes

  unsigned short* w1t = (unsigned short*)(ws + OFF_W1T);
  unsigned short* w2t = (unsigned short*)(ws + OFF_W2T);
  unsigned short* xb  = (unsigned short*)(ws + OFF_XB);
  unsigned short* h   = (unsigned short*)(ws + OFF_H);
  _Float16* xh        = (_Float16*)(ws + OFF_XH);
  _Float16* xl        = (_Float16*)(ws + OFF_XL);
  _Float16* wth       = (_Float16*)(ws + OFF_WTH);
  _Float16* wtl       = (_Float16*)(ws + OFF_WTL);
  int* tokList        = (int*)(ws + OFF_TOK);
  float* gateList     = (float*)(ws + OFF_GATE);
  int* tIdx           = (int*)(ws + OFF_TIDX);
  float* tGate        = (float*)(ws + OFF_TG);
  float* logits       = (float*)(ws + OFF_LOG);
  int* counts         = (int*)(ws + OFF_META);
  int* fill           = (int*)(ws + OFF_META + 32);
  int* offsets        = (int*)(ws + OFF_META + 64);
  int* nTiles         = (int*)(ws + OFF_META + 128);
  int4* desc          = (int4*)(ws + OFF_META + 160);

  hipMemsetAsync(ws + OFF_TOK, 0, (size_t)2 * HROWS * 4, stream);
  hipMemsetAsync(ws + OFF_LOG, 0, (size_t)T_TOK * NE * 4, stream);
  hipMemsetAsync(ws + OFF_META, 0, 64, stream);

  split_x_kernel<<<dim3((T_TOK * DM / 4) / 256), dim3(256), 0, stream>>>(x, xb, xh, xl);
  transpose_split_w_kernel<<<dim3(DM / 32, DM / 32), dim3(32, 8), 0, stream>>>(Wg1, wth, wtl);
  transpose_cast_kernel<<<dim3(DFF / 32, DM / 32, NE), dim3(32, 8), 0, stream>>>(W1, w1t, DM, DFF);
  transpose_cast_kernel<<<dim3(DM / 32, DFF / 32, NE), dim3(32, 8), 0, stream>>>(W2, w2t, DFF, DM);

  router_mfma_kernel<<<dim3(DM / 128, T_TOK / 128), dim3(256), 0, stream>>>(xh, xl, wth, wtl,
                                                                            bg1, Wg2, logits);
  topk_small_kernel<<<dim3(T_TOK / 256), dim3(256), 0, stream>>>(logits, tIdx, tGate, counts);
  build_tiles_kernel<<<dim3(1), dim3(64), 0, stream>>>(counts, offsets, desc, nTiles);
  scatter_kernel<<<dim3((2 * T_TOK) / 256), dim3(256), 0, stream>>>(tIdx, tGate, offsets, fill,
                                                                    tokList, gateList);

  ffn1_kernel<<<dim3(DFF / 128, MAX_TILES), dim3(256), 0, stream>>>(xb, w1t, tokList, desc,
                                                                    nTiles, h);
  ffn2_kernel<<<dim3(DM / 128, MAX_TILES), dim3(256), 0, stream>>>(h, w2t, tokList, gateList,
                                                                   desc, nTiles, y);
}

// Round 7
// 781.737 us; speedup vs baseline: 1.3999x; 1.0292x over previous
//
#include <hip/hip_runtime.h>
#include <hip/hip_bf16.h>
#include <math.h>

#define T_TOK 8192
#define DM 1024
#define DFF 4096
#define NE 8
#define HROWS 16512
#define MAX_TILES 136
#define TPX 17  // tiles per XCD class (MAX_TILES/8)

typedef __attribute__((ext_vector_type(8))) short bf16x8;
typedef __attribute__((ext_vector_type(4))) float f32x4;
typedef __attribute__((ext_vector_type(8))) _Float16 f16x8;
typedef __attribute__((ext_vector_type(4))) _Float16 f16x4;

__device__ __forceinline__ void async16(const void* g, void* l) {
  __builtin_amdgcn_global_load_lds((const __attribute__((address_space(1))) void*)g,
                                   (__attribute__((address_space(3))) void*)l, 16, 0, 0);
}

__device__ __forceinline__ unsigned short f2b(float f) {
  __hip_bfloat16 h = __float2bfloat16(f);
  return *reinterpret_cast<unsigned short*>(&h);
}

__device__ __forceinline__ float tanh_fast(float z) {
  return 1.f - 2.f / (__expf(2.f * z) + 1.f);
}

__device__ __forceinline__ float gelu_fast(float v) {
  float u = v + 0.044715f * v * v * v;
  return v / (1.f + __expf(-1.5957691216057308f * u));
}

// ---------------- split x: fp32 -> bf16 (for FFN) + f16 hi/lo (for router) ----------------
__global__ void split_x_kernel(const float* __restrict__ in, unsigned short* __restrict__ xb,
                               _Float16* __restrict__ xh, _Float16* __restrict__ xl) {
  int i = blockIdx.x * blockDim.x + threadIdx.x;
  float4 v = reinterpret_cast<const float4*>(in)[i];
  ushort4 ob;
  f16x4 oh, ol;
  float f, hf;
  f = v.x; oh[0] = (_Float16)f; hf = (float)oh[0]; ol[0] = (_Float16)((f - hf) * 2048.0f); ob.x = f2b(f);
  f = v.y; oh[1] = (_Float16)f; hf = (float)oh[1]; ol[1] = (_Float16)((f - hf) * 2048.0f); ob.y = f2b(f);
  f = v.z; oh[2] = (_Float16)f; hf = (float)oh[2]; ol[2] = (_Float16)((f - hf) * 2048.0f); ob.z = f2b(f);
  f = v.w; oh[3] = (_Float16)f; hf = (float)oh[3]; ol[3] = (_Float16)((f - hf) * 2048.0f); ob.w = f2b(f);
  reinterpret_cast<ushort4*>(xb)[i] = ob;
  reinterpret_cast<f16x4*>(xh)[i] = oh;
  reinterpret_cast<f16x4*>(xl)[i] = ol;
}

// ---------------- transpose + split Wg1: [k][n] fp32 -> [n][k] f16 hi/lo ----------------
__global__ void transpose_split_w_kernel(const float* __restrict__ in,
                                         _Float16* __restrict__ outh, _Float16* __restrict__ outl) {
  __shared__ float tile[32][33];
  int r0 = blockIdx.y * 32, c0 = blockIdx.x * 32;
  int tx = threadIdx.x, ty = threadIdx.y;  // (32,8)
#pragma unroll
  for (int i = 0; i < 32; i += 8) tile[ty + i][tx] = in[(size_t)(r0 + ty + i) * DM + c0 + tx];
  __syncthreads();
#pragma unroll
  for (int i = 0; i < 32; i += 8) {
    float f = tile[tx][ty + i];
    _Float16 h = (_Float16)f;
    size_t idx = (size_t)(c0 + ty + i) * DM + r0 + tx;
    outh[idx] = h;
    outl[idx] = (_Float16)((f - (float)h) * 2048.0f);
  }
}

// ---------------- transpose + cast: in fp32 [E][R][C] -> out bf16 [E][C][R] ----------------
__global__ void transpose_cast_kernel(const float* __restrict__ in, unsigned short* __restrict__ out,
                                      int R, int C) {
  __shared__ float tile[32][33];
  int e = blockIdx.z;
  int r0 = blockIdx.y * 32, c0 = blockIdx.x * 32;
  const float* src = in + (size_t)e * R * C;
  unsigned short* dst = out + (size_t)e * R * C;
  int tx = threadIdx.x, ty = threadIdx.y;  // (32,8)
#pragma unroll
  for (int i = 0; i < 32; i += 8) tile[ty + i][tx] = src[(size_t)(r0 + ty + i) * C + c0 + tx];
  __syncthreads();
#pragma unroll
  for (int i = 0; i < 32; i += 8) dst[(size_t)(c0 + ty + i) * R + r0 + tx] = f2b(tile[tx][ty + i]);
}

// ---------------- MFMA router: logits += tanh(X@Wg1+bg1)[:,n-slice] @ Wg2[n-slice,:] ----------------
__global__ __launch_bounds__(256) void router_mfma_kernel(
    const _Float16* __restrict__ xh, const _Float16* __restrict__ xl,
    const _Float16* __restrict__ wth, const _Float16* __restrict__ wtl,
    const float* __restrict__ bg1, const float* __restrict__ Wg2,
    float* __restrict__ logits) {
  __shared__ __align__(16) char AB[2][32768];
  __shared__ float lgt[128 * 2 * NE];

  const int tid = threadIdx.x;
  const int lane = tid & 63;
  const int w = tid >> 6;
  const int n0 = blockIdx.x * 128, m0 = blockIdx.y * 128;

  const int r0 = w * 16 + (lane >> 2);
  const int r1 = r0 + 64;
  const int sp = lane & 3;
  const int k0s = (sp ^ ((r0 >> 1) & 3)) * 8;
  const int k1s = (sp ^ ((r1 >> 1) & 3)) * 8;

  const _Float16* gAh0 = xh + (size_t)(m0 + r0) * DM + k0s;
  const _Float16* gAh1 = xh + (size_t)(m0 + r1) * DM + k1s;
  const _Float16* gAl0 = xl + (size_t)(m0 + r0) * DM + k0s;
  const _Float16* gAl1 = xl + (size_t)(m0 + r1) * DM + k1s;
  const _Float16* gBh0 = wth + (size_t)(n0 + r0) * DM + k0s;
  const _Float16* gBh1 = wth + (size_t)(n0 + r1) * DM + k1s;
  const _Float16* gBl0 = wtl + (size_t)(n0 + r0) * DM + k0s;
  const _Float16* gBl1 = wtl + (size_t)(n0 + r1) * DM + k1s;

  const int wr = (w >> 1) * 64, wc = (w & 1) * 64;
  const int l15 = lane & 15, ls = lane >> 4;

  f32x4 zero = {0.f, 0.f, 0.f, 0.f};
  f32x4 acc_hh[4][4], acc_c[4][4];
#pragma unroll
  for (int i = 0; i < 4; i++)
#pragma unroll
    for (int j = 0; j < 4; j++) { acc_hh[i][j] = zero; acc_c[i][j] = zero; }

  auto stage = [&](int buf, int kt) {
    char* b = &AB[buf][0] + w * 1024;
    async16(gAh0 + kt, b);
    async16(gAh1 + kt, b + 4096);
    async16(gAl0 + kt, b + 8192);
    async16(gAl1 + kt, b + 8192 + 4096);
    async16(gBh0 + kt, b + 16384);
    async16(gBh1 + kt, b + 16384 + 4096);
    async16(gBl0 + kt, b + 24576);
    async16(gBl1 + kt, b + 24576 + 4096);
  };
  auto computeTile = [&](int cur) {
    const char* base = &AB[cur][0];
    f16x8 ah[4], bh[4], tmp[4];
#pragma unroll
    for (int i = 0; i < 4; i++) {
      int ar = wr + i * 16 + l15;
      ah[i] = *(const f16x8*)(base + ar * 64 + ((ls ^ ((ar >> 1) & 3)) << 4));
    }
#pragma unroll
    for (int j = 0; j < 4; j++) {
      int br = wc + j * 16 + l15;
      bh[j] = *(const f16x8*)(base + 16384 + br * 64 + ((ls ^ ((br >> 1) & 3)) << 4));
    }
#pragma unroll
    for (int i = 0; i < 4; i++)
#pragma unroll
      for (int j = 0; j < 4; j++)
        acc_hh[i][j] = __builtin_amdgcn_mfma_f32_16x16x32_f16(ah[i], bh[j], acc_hh[i][j], 0, 0, 0);
#pragma unroll
    for (int j = 0; j < 4; j++) {
      int br = wc + j * 16 + l15;
      tmp[j] = *(const f16x8*)(base + 24576 + br * 64 + ((ls ^ ((br >> 1) & 3)) << 4));
    }
#pragma unroll
    for (int i = 0; i < 4; i++)
#pragma unroll
      for (int j = 0; j < 4; j++)
        acc_c[i][j] = __builtin_amdgcn_mfma_f32_16x16x32_f16(ah[i], tmp[j], acc_c[i][j], 0, 0, 0);
#pragma unroll
    for (int i = 0; i < 4; i++) {
      int ar = wr + i * 16 + l15;
      tmp[i] = *(const f16x8*)(base + 8192 + ar * 64 + ((ls ^ ((ar >> 1) & 3)) << 4));
    }
#pragma unroll
    for (int i = 0; i < 4; i++)
#pragma unroll
      for (int j = 0; j < 4; j++)
        acc_c[i][j] = __builtin_amdgcn_mfma_f32_16x16x32_f16(tmp[i], bh[j], acc_c[i][j], 0, 0, 0);
  };

  const int NIT = DM / 32;
  stage(0, 0);
  __syncthreads();
#pragma unroll 2
  for (int t = 0; t < NIT - 1; t++) {
    const int cur = t & 1;
    stage(cur ^ 1, (t + 1) * 32);
    computeTile(cur);
    __syncthreads();
  }
  computeTile((NIT - 1) & 1);

  float w2r[4][8];
  float bias[4];
#pragma unroll
  for (int j = 0; j < 4; j++) {
    int gn = n0 + wc + j * 16 + l15;
    bias[j] = bg1[gn];
    float4 u = *(const float4*)(Wg2 + (size_t)gn * NE);
    float4 v = *(const float4*)(Wg2 + (size_t)gn * NE + 4);
    w2r[j][0] = u.x; w2r[j][1] = u.y; w2r[j][2] = u.z; w2r[j][3] = u.w;
    w2r[j][4] = v.x; w2r[j][5] = v.y; w2r[j][6] = v.z; w2r[j][7] = v.w;
  }
  const float inv2k = 1.0f / 2048.0f;
  const int half = wc >> 6;
  const bool b3 = (l15 & 8) != 0, b2 = (l15 & 4) != 0, b1 = (l15 & 2) != 0;
#pragma unroll
  for (int i = 0; i < 4; i++) {
#pragma unroll
    for (int r = 0; r < 4; r++) {
      float s[8] = {0.f, 0.f, 0.f, 0.f, 0.f, 0.f, 0.f, 0.f};
#pragma unroll
      for (int j = 0; j < 4; j++) {
        float hv = tanh_fast(acc_hh[i][j][r] + acc_c[i][j][r] * inv2k + bias[j]);
#pragma unroll
        for (int e = 0; e < NE; e++) s[e] = fmaf(hv, w2r[j][e], s[e]);
      }
      float t4_[4], t2_[2], t1_;
#pragma unroll
      for (int q = 0; q < 4; q++) {
        float snd = b3 ? s[q] : s[q + 4];
        float rcv = __shfl_xor(snd, 8);
        t4_[q] = (b3 ? s[q + 4] : s[q]) + rcv;
      }
#pragma unroll
      for (int q = 0; q < 2; q++) {
        float snd = b2 ? t4_[q] : t4_[q + 2];
        float rcv = __shfl_xor(snd, 4);
        t2_[q] = (b2 ? t4_[q + 2] : t4_[q]) + rcv;
      }
      {
        float snd = b1 ? t2_[0] : t2_[1];
        float rcv = __shfl_xor(snd, 2);
        t1_ = (b1 ? t2_[1] : t2_[0]) + rcv;
      }
      t1_ += __shfl_xor(t1_, 1);
      int m = wr + i * 16 + ls * 4 + r;
      if (!(l15 & 1)) lgt[m * (2 * NE) + half * NE + (l15 >> 1)] = t1_;
    }
  }
  __syncthreads();
#pragma unroll
  for (int q = 0; q < 4; q++) {
    int idx = tid * 4 + q;
    int m = idx >> 3, e = idx & 7;
    float v = lgt[m * (2 * NE) + e] + lgt[m * (2 * NE) + NE + e];
    atomicAdd(&logits[(size_t)(m0 + m) * NE + e], v);
  }
}

// ---------------- top-2 over 8 logits per token ----------------
__global__ __launch_bounds__(256) void topk_small_kernel(
    const float* __restrict__ logits, int* __restrict__ tIdx, float* __restrict__ tGate,
    int* __restrict__ counts) {
  __shared__ int lc[NE];
  const int tid = threadIdx.x;
  if (tid < NE) lc[tid] = 0;
  __syncthreads();
  int t = blockIdx.x * 256 + tid;
  float p[NE];
  float4 p0 = *(const float4*)(logits + (size_t)t * NE);
  float4 p1 = *(const float4*)(logits + (size_t)t * NE + 4);
  p[0] = p0.x; p[1] = p0.y; p[2] = p0.z; p[3] = p0.w;
  p[4] = p1.x; p[5] = p1.y; p[6] = p1.z; p[7] = p1.w;
  float v1 = -1e30f, v2 = -1e30f; int i1 = 0, i2 = 1;
#pragma unroll
  for (int e = 0; e < NE; e++) {
    float v = p[e];
    if (v > v1) { v2 = v1; i2 = i1; v1 = v; i1 = e; }
    else if (v > v2) { v2 = v; i2 = e; }
  }
  float mx = v1;
  float s = 0.f;
#pragma unroll
  for (int e = 0; e < NE; e++) s += __expf(p[e] - mx);
  float inv = 1.f / s;
  float g1 = __expf(p[i1] - mx) * inv;
  float g2 = __expf(p[i2] - mx) * inv;
  float den = 1.f / (g1 + g2 + 1e-6f);
  tIdx[2 * t] = i1; tIdx[2 * t + 1] = i2;
  tGate[2 * t] = g1 * den; tGate[2 * t + 1] = g2 * den;
  atomicAdd(&lc[i1], 1);
  atomicAdd(&lc[i2], 1);
  __syncthreads();
  if (tid < NE) atomicAdd(&counts[tid], lc[tid]);
}

// ---------------- prefix sums + tile descriptors (single thread) ----------------
__global__ void build_tiles_kernel(const int* __restrict__ counts, int* __restrict__ offsets,
                                   int4* __restrict__ desc, int* __restrict__ nTiles) {
  if (threadIdx.x != 0 || blockIdx.x != 0) return;
  int off = 0, nt = 0;
  for (int e = 0; e < NE; e++) {
    offsets[e] = off;
    int c = counts[e];
    if (c < 0) c = 0;
    if (c > 2 * T_TOK) c = 2 * T_TOK;
    for (int r = 0; r < c && nt < MAX_TILES; r += 128) {
      int v = c - r; if (v > 128) v = 128;
      desc[nt++] = make_int4(e, off + r, v, 0);
    }
    off += c;
    if (off > 2 * T_TOK) off = 2 * T_TOK;
  }
  offsets[NE] = off;
  *nTiles = nt;
}

// ---------------- scatter tokens into expert-grouped lists ----------------
__global__ void scatter_kernel(const int* __restrict__ tIdx, const float* __restrict__ tGate,
                               const int* __restrict__ offsets, int* __restrict__ fill,
                               int* __restrict__ tokList, float* __restrict__ gateList) {
  int id = blockIdx.x * blockDim.x + threadIdx.x;
  if (id >= 2 * T_TOK) return;
  int e = tIdx[id] & 7;
  int pos = atomicAdd(&fill[e], 1);
  int row = offsets[e] + pos;
  if (row < 0 || row >= 2 * T_TOK) return;
  tokList[row] = id >> 1;
  gateList[row] = tGate[id];
}

// ---------------- FFN1: h = gelu(gather(xb) @ W1_e), BK=32, 2-phase dbuf, XCD-affine ----------------
__global__ __launch_bounds__(256) void ffn1_kernel(
    const unsigned short* __restrict__ xb, const unsigned short* __restrict__ w1t,
    const int* __restrict__ tokList, const int4* __restrict__ desc,
    const int* __restrict__ nTiles, unsigned short* __restrict__ h) {
  // XCD-affinity decode: all n-blocks of a tile share g%8 -> same XCD L2
  const int g = blockIdx.x;
  const int tileIdx = (g & 7) * TPX + ((g >> 3) % TPX);
  const int nb = g / (8 * TPX);
  if (tileIdx >= *nTiles) return;
  int4 d = desc[tileIdx];
  const int e = d.x, rowStart = d.y, valid = d.z;
  const int n0 = nb * 128;

  __shared__ __align__(16) char AB[2][16384];

  const int tid = threadIdx.x;
  const int lane = tid & 63;
  const int w = tid >> 6;

  const int r0 = w * 16 + (lane >> 2);
  const int r1 = r0 + 64;
  const int sp = lane & 3;
  const int k0s = (sp ^ ((r0 >> 1) & 3)) * 8;
  const int k1s = (sp ^ ((r1 >> 1) & 3)) * 8;

  const unsigned short* gA0 = xb + (size_t)(tokList[rowStart + r0] & (T_TOK - 1)) * DM + k0s;
  const unsigned short* gA1 = xb + (size_t)(tokList[rowStart + r1] & (T_TOK - 1)) * DM + k1s;
  const unsigned short* gB0 = w1t + ((size_t)e * DFF + n0 + r0) * DM + k0s;
  const unsigned short* gB1 = w1t + ((size_t)e * DFF + n0 + r1) * DM + k1s;

  const int wr = (w >> 1) * 64, wc = (w & 1) * 64;
  const int l15 = lane & 15, ls = lane >> 4;

  f32x4 zero = {0.f, 0.f, 0.f, 0.f};
  f32x4 acc[4][4];
#pragma unroll
  for (int i = 0; i < 4; i++)
#pragma unroll
    for (int j = 0; j < 4; j++) acc[i][j] = zero;

  auto stage = [&](int buf, int kt) {
    char* dA = &AB[buf][0] + w * 1024;
    char* dB = dA + 8192;
    async16(gA0 + kt, dA);
    async16(gA1 + kt, dA + 4096);
    async16(gB0 + kt, dB);
    async16(gB1 + kt, dB + 4096);
  };
  auto computeTile = [&](int cur) {
    const char* rA = &AB[cur][0];
    const char* rB = rA + 8192;
    bf16x8 af[4], bfv[4];
#pragma unroll
    for (int i = 0; i < 4; i++) {
      int ar = wr + i * 16 + l15;
      af[i] = *(const bf16x8*)(rA + ar * 64 + ((ls ^ ((ar >> 1) & 3)) << 4));
    }
#pragma unroll
    for (int j = 0; j < 4; j++) {
      int br = wc + j * 16 + l15;
      bfv[j] = *(const bf16x8*)(rB + br * 64 + ((ls ^ ((br >> 1) & 3)) << 4));
    }
#pragma unroll
    for (int i = 0; i < 4; i++)
#pragma unroll
      for (int j = 0; j < 4; j++)
        acc[i][j] = __builtin_amdgcn_mfma_f32_16x16x32_bf16(af[i], bfv[j], acc[i][j], 0, 0, 0);
  };

  const int NIT = DM / 32;
  stage(0, 0);
  __syncthreads();
#pragma unroll 2
  for (int t = 0; t < NIT - 1; t++) {
    const int cur = t & 1;
    stage(cur ^ 1, (t + 1) * 32);
    computeTile(cur);
    __syncthreads();
  }
  computeTile((NIT - 1) & 1);

#pragma unroll
  for (int i = 0; i < 4; i++) {
#pragma unroll
    for (int r = 0; r < 4; r++) {
      int m = wr + i * 16 + ls * 4 + r;
      if (m < valid) {
        size_t base = (size_t)(rowStart + m) * DFF + n0 + wc;
#pragma unroll
        for (int j = 0; j < 4; j++) {
          h[base + j * 16 + l15] = f2b(gelu_fast(acc[i][j][r]));
        }
      }
    }
  }
}

// ---------------- FFN2: y += gate * (h @ W2_e), BK=32, 2-phase dbuf, XCD-affine ----------------
__global__ __launch_bounds__(256) void ffn2_kernel(
    const unsigned short* __restrict__ h, const unsigned short* __restrict__ w2t,
    const int* __restrict__ tokList, const float* __restrict__ gateList,
    const int4* __restrict__ desc, const int* __restrict__ nTiles,
    float* __restrict__ y) {
  const int g = blockIdx.x;
  const int tileIdx = (g & 7) * TPX + ((g >> 3) % TPX);
  const int nb = g / (8 * TPX);
  if (tileIdx >= *nTiles) return;
  int4 d = desc[tileIdx];
  const int e = d.x, rowStart = d.y, valid = d.z;
  const int n0 = nb * 128;

  __shared__ __align__(16) char AB[2][16384];

  const int tid = threadIdx.x;
  const int lane = tid & 63;
  const int w = tid >> 6;

  const int r0 = w * 16 + (lane >> 2);
  const int r1 = r0 + 64;
  const int sp = lane & 3;
  const int k0s = (sp ^ ((r0 >> 1) & 3)) * 8;
  const int k1s = (sp ^ ((r1 >> 1) & 3)) * 8;

  const unsigned short* gA0 = h + (size_t)(rowStart + r0) * DFF + k0s;
  const unsigned short* gA1 = h + (size_t)(rowStart + r1) * DFF + k1s;
  const unsigned short* gB0 = w2t + ((size_t)e * DM + n0 + r0) * DFF + k0s;
  const unsigned short* gB1 = w2t + ((size_t)e * DM + n0 + r1) * DFF + k1s;

  const int wr = (w >> 1) * 64, wc = (w & 1) * 64;
  const int l15 = lane & 15, ls = lane >> 4;

  f32x4 zero = {0.f, 0.f, 0.f, 0.f};
  f32x4 acc[4][4];
#pragma unroll
  for (int i = 0; i < 4; i++)
#pragma unroll
    for (int j = 0; j < 4; j++) acc[i][j] = zero;

  auto stage = [&](int buf, int kt) {
    char* dA = &AB[buf][0] + w * 1024;
    char* dB = dA + 8192;
    async16(gA0 + kt, dA);
    async16(gA1 + kt, dA + 4096);
    async16(gB0 + kt, dB);
    async16(gB1 + kt, dB + 4096);
  };
  auto computeTile = [&](int cur) {
    const char* rA = &AB[cur][0];
    const char* rB = rA + 8192;
    bf16x8 af[4], bfv[4];
#pragma unroll
    for (int i = 0; i < 4; i++) {
      int ar = wr + i * 16 + l15;
      af[i] = *(const bf16x8*)(rA + ar * 64 + ((ls ^ ((ar >> 1) & 3)) << 4));
    }
#pragma unroll
    for (int j = 0; j < 4; j++) {
      int br = wc + j * 16 + l15;
      bfv[j] = *(const bf16x8*)(rB + br * 64 + ((ls ^ ((br >> 1) & 3)) << 4));
    }
#pragma unroll
    for (int i = 0; i < 4; i++)
#pragma unroll
      for (int j = 0; j < 4; j++)
        acc[i][j] = __builtin_amdgcn_mfma_f32_16x16x32_bf16(af[i], bfv[j], acc[i][j], 0, 0, 0);
  };

  const int NIT = DFF / 32;
  stage(0, 0);
  __syncthreads();
#pragma unroll 2
  for (int t = 0; t < NIT - 1; t++) {
    const int cur = t & 1;
    stage(cur ^ 1, (t + 1) * 32);
    computeTile(cur);
    __syncthreads();
  }
  computeTile((NIT - 1) & 1);

#pragma unroll
  for (int i = 0; i < 4; i++) {
#pragma unroll
    for (int r = 0; r < 4; r++) {
      int m = wr + i * 16 + ls * 4 + r;
      if (m < valid) {
        int row = rowStart + m;
        int tok = tokList[row] & (T_TOK - 1);
        float g2 = gateList[row];
        float* yr = y + (size_t)tok * DM + n0 + wc;
#pragma unroll
        for (int j = 0; j < 4; j++) {
          atomicAdd(&yr[j * 16 + l15], g2 * acc[i][j][r]);
        }
      }
    }
  }
}

// ---------------- host launch ----------------
extern "C" void kernel_launch(void* const* d_in, const int* in_sizes, int n_in,
                              void* d_out, int out_size, void* d_ws, size_t ws_size,
                              hipStream_t stream) {
  const float* x   = (const float*)d_in[0];
  const float* Wg1 = (const float*)d_in[1];
  const float* bg1 = (const float*)d_in[2];
  const float* Wg2 = (const float*)d_in[3];
  const float* W1  = (const float*)d_in[4];
  const float* W2  = (const float*)d_in[5];
  float* y = (float*)d_out;
  char* ws = (char*)d_ws;

  const size_t SZ_W1T = (size_t)NE * DFF * DM * 2;
  const size_t OFF_W1T = 0;
  const size_t OFF_W2T = OFF_W1T + SZ_W1T;
  const size_t OFF_XB  = OFF_W2T + SZ_W1T;
  const size_t OFF_H   = OFF_XB + (size_t)T_TOK * DM * 2;
  const size_t OFF_TOK = OFF_H + (size_t)HROWS * DFF * 2;
  const size_t OFF_GATE = OFF_TOK + (size_t)HROWS * 4;
  const size_t OFF_TIDX = OFF_GATE + (size_t)HROWS * 4;
  const size_t OFF_TG   = OFF_TIDX + (size_t)2 * T_TOK * 4;
  const size_t OFF_LOG  = OFF_TG + (size_t)2 * T_TOK * 4;
  const size_t OFF_META = OFF_LOG + (size_t)T_TOK * NE * 4;
  const size_t NEED = OFF_META + 4096;

  const size_t OFF_XH  = OFF_H;
  const size_t OFF_XL  = OFF_XH + (size_t)T_TOK * DM * 2;
  const size_t OFF_WTH = OFF_XL + (size_t)T_TOK * DM * 2;
  const size_t OFF_WTL = OFF_WTH + (size_t)DM * DM * 2;

  hipMemsetAsync(d_out, 0, (size_t)out_size * 4, stream);
  if (ws_size < NEED) return;

  unsigned short* w1t = (unsigned short*)(ws + OFF_W1T);
  unsigned short* w2t = (unsigned short*)(ws + OFF_W2T);
  unsigned short* xb  = (unsigned short*)(ws + OFF_XB);
  unsigned short* h   = (unsigned short*)(ws + OFF_H);
  _Float16* xh        = (_Float16*)(ws + OFF_XH);
  _Float16* xl        = (_Float16*)(ws + OFF_XL);
  _Float16* wth       = (_Float16*)(ws + OFF_WTH);
  _Float16* wtl       = (_Float16*)(ws + OFF_WTL);
  int* tokList        = (int*)(ws + OFF_TOK);
  float* gateList     = (float*)(ws + OFF_GATE);
  int* tIdx           = (int*)(ws + OFF_TIDX);
  float* tGate        = (float*)(ws + OFF_TG);
  float* logits       = (float*)(ws + OFF_LOG);
  int* counts         = (int*)(ws + OFF_META);
  int* fill           = (int*)(ws + OFF_META + 32);
  int* offsets        = (int*)(ws + OFF_META + 64);
  int* nTiles         = (int*)(ws + OFF_META + 128);
  int4* desc          = (int4*)(ws + OFF_META + 160);

  hipMemsetAsync(ws + OFF_TOK, 0, (size_t)2 * HROWS * 4, stream);
  hipMemsetAsync(ws + OFF_LOG, 0, (size_t)T_TOK * NE * 4, stream);
  hipMemsetAsync(ws + OFF_META, 0, 64, stream);

  split_x_kernel<<<dim3((T_TOK * DM / 4) / 256), dim3(256), 0, stream>>>(x, xb, xh, xl);
  transpose_split_w_kernel<<<dim3(DM / 32, DM / 32), dim3(32, 8), 0, stream>>>(Wg1, wth, wtl);
  transpose_cast_kernel<<<dim3(DFF / 32, DM / 32, NE), dim3(32, 8), 0, stream>>>(W1, w1t, DM, DFF);
  transpose_cast_kernel<<<dim3(DM / 32, DFF / 32, NE), dim3(32, 8), 0, stream>>>(W2, w2t, DFF, DM);

  router_mfma_kernel<<<dim3(DM / 128, T_TOK / 128), dim3(256), 0, stream>>>(xh, xl, wth, wtl,
                                                                            bg1, Wg2, logits);
  topk_small_kernel<<<dim3(T_TOK / 256), dim3(256), 0, stream>>>(logits, tIdx, tGate, counts);
  build_tiles_kernel<<<dim3(1), dim3(64), 0, stream>>>(counts, offsets, desc, nTiles);
  scatter_kernel<<<dim3((2 * T_TOK) / 256), dim3(256), 0, stream>>>(tIdx, tGate, offsets, fill,
                                                                    tokList, gateList);

  // 1-D grids with XCD-affinity decode inside the kernel
  ffn1_kernel<<<dim3((DFF / 128) * MAX_TILES), dim3(256), 0, stream>>>(xb, w1t, tokList, desc,
                                                                       nTiles, h);
  ffn2_kernel<<<dim3((DM / 128) * MAX_TILES), dim3(256), 0, stream>>>(h, w2t, tokList, gateList,
                                                                      desc, nTiles, y);
}

// Round 8
// 710.180 us; speedup vs baseline: 1.5410x; 1.1008x over previous
//
#include <hip/hip_runtime.h>
#include <hip/hip_bf16.h>
#include <math.h>

#define T_TOK 8192
#define DM 1024
#define DFF 4096
#define NE 8
#define HROWS 16512
#define MAX_TILES 136
#define TPX 17  // tiles per XCD class (MAX_TILES/8)

typedef __attribute__((ext_vector_type(8))) short bf16x8;
typedef __attribute__((ext_vector_type(4))) float f32x4;
typedef __attribute__((ext_vector_type(8))) _Float16 f16x8;
typedef __attribute__((ext_vector_type(4))) _Float16 f16x4;

__device__ __forceinline__ void async16(const void* g, void* l) {
  __builtin_amdgcn_global_load_lds((const __attribute__((address_space(1))) void*)g,
                                   (__attribute__((address_space(3))) void*)l, 16, 0, 0);
}

__device__ __forceinline__ unsigned short f2b(float f) {
  __hip_bfloat16 h = __float2bfloat16(f);
  return *reinterpret_cast<unsigned short*>(&h);
}

__device__ __forceinline__ float tanh_fast(float z) {
  return 1.f - 2.f / (__expf(2.f * z) + 1.f);
}

__device__ __forceinline__ float gelu_fast(float v) {
  float u = v + 0.044715f * v * v * v;
  return v / (1.f + __expf(-1.5957691216057308f * u));
}

// ---------------- split x: fp32 -> bf16 (for FFN) + f16 hi/lo (for router) ----------------
__global__ void split_x_kernel(const float* __restrict__ in, unsigned short* __restrict__ xb,
                               _Float16* __restrict__ xh, _Float16* __restrict__ xl) {
  int i = blockIdx.x * blockDim.x + threadIdx.x;
  float4 v = reinterpret_cast<const float4*>(in)[i];
  ushort4 ob;
  f16x4 oh, ol;
  float f, hf;
  f = v.x; oh[0] = (_Float16)f; hf = (float)oh[0]; ol[0] = (_Float16)((f - hf) * 2048.0f); ob.x = f2b(f);
  f = v.y; oh[1] = (_Float16)f; hf = (float)oh[1]; ol[1] = (_Float16)((f - hf) * 2048.0f); ob.y = f2b(f);
  f = v.z; oh[2] = (_Float16)f; hf = (float)oh[2]; ol[2] = (_Float16)((f - hf) * 2048.0f); ob.z = f2b(f);
  f = v.w; oh[3] = (_Float16)f; hf = (float)oh[3]; ol[3] = (_Float16)((f - hf) * 2048.0f); ob.w = f2b(f);
  reinterpret_cast<ushort4*>(xb)[i] = ob;
  reinterpret_cast<f16x4*>(xh)[i] = oh;
  reinterpret_cast<f16x4*>(xl)[i] = ol;
}

// ---------------- transpose + split Wg1: [k][n] fp32 -> [n][k] f16 hi/lo ----------------
__global__ void transpose_split_w_kernel(const float* __restrict__ in,
                                         _Float16* __restrict__ outh, _Float16* __restrict__ outl) {
  __shared__ float tile[32][33];
  int r0 = blockIdx.y * 32, c0 = blockIdx.x * 32;
  int tx = threadIdx.x, ty = threadIdx.y;  // (32,8)
#pragma unroll
  for (int i = 0; i < 32; i += 8) tile[ty + i][tx] = in[(size_t)(r0 + ty + i) * DM + c0 + tx];
  __syncthreads();
#pragma unroll
  for (int i = 0; i < 32; i += 8) {
    float f = tile[tx][ty + i];
    _Float16 h = (_Float16)f;
    size_t idx = (size_t)(c0 + ty + i) * DM + r0 + tx;
    outh[idx] = h;
    outl[idx] = (_Float16)((f - (float)h) * 2048.0f);
  }
}

// ---------------- transpose + cast: in fp32 [E][R][C] -> out bf16 [E][C][R] ----------------
__global__ void transpose_cast_kernel(const float* __restrict__ in, unsigned short* __restrict__ out,
                                      int R, int C) {
  __shared__ float tile[32][33];
  int e = blockIdx.z;
  int r0 = blockIdx.y * 32, c0 = blockIdx.x * 32;
  const float* src = in + (size_t)e * R * C;
  unsigned short* dst = out + (size_t)e * R * C;
  int tx = threadIdx.x, ty = threadIdx.y;  // (32,8)
#pragma unroll
  for (int i = 0; i < 32; i += 8) tile[ty + i][tx] = src[(size_t)(r0 + ty + i) * C + c0 + tx];
  __syncthreads();
#pragma unroll
  for (int i = 0; i < 32; i += 8) dst[(size_t)(c0 + ty + i) * R + r0 + tx] = f2b(tile[tx][ty + i]);
}

// ---------------- MFMA router: logits += tanh(X@Wg1+bg1)[:,n-slice] @ Wg2[n-slice,:] ----------------
__global__ __launch_bounds__(256) void router_mfma_kernel(
    const _Float16* __restrict__ xh, const _Float16* __restrict__ xl,
    const _Float16* __restrict__ wth, const _Float16* __restrict__ wtl,
    const float* __restrict__ bg1, const float* __restrict__ Wg2,
    float* __restrict__ logits) {
  __shared__ __align__(16) char AB[2][32768];
  __shared__ float lgt[128 * 2 * NE];

  const int tid = threadIdx.x;
  const int lane = tid & 63;
  const int w = tid >> 6;
  const int n0 = blockIdx.x * 128, m0 = blockIdx.y * 128;

  const int r0 = w * 16 + (lane >> 2);
  const int r1 = r0 + 64;
  const int sp = lane & 3;
  const int k0s = (sp ^ ((r0 >> 1) & 3)) * 8;
  const int k1s = (sp ^ ((r1 >> 1) & 3)) * 8;

  const _Float16* gAh0 = xh + (size_t)(m0 + r0) * DM + k0s;
  const _Float16* gAh1 = xh + (size_t)(m0 + r1) * DM + k1s;
  const _Float16* gAl0 = xl + (size_t)(m0 + r0) * DM + k0s;
  const _Float16* gAl1 = xl + (size_t)(m0 + r1) * DM + k1s;
  const _Float16* gBh0 = wth + (size_t)(n0 + r0) * DM + k0s;
  const _Float16* gBh1 = wth + (size_t)(n0 + r1) * DM + k1s;
  const _Float16* gBl0 = wtl + (size_t)(n0 + r0) * DM + k0s;
  const _Float16* gBl1 = wtl + (size_t)(n0 + r1) * DM + k1s;

  const int wr = (w >> 1) * 64, wc = (w & 1) * 64;
  const int l15 = lane & 15, ls = lane >> 4;

  f32x4 zero = {0.f, 0.f, 0.f, 0.f};
  f32x4 acc_hh[4][4], acc_c[4][4];
#pragma unroll
  for (int i = 0; i < 4; i++)
#pragma unroll
    for (int j = 0; j < 4; j++) { acc_hh[i][j] = zero; acc_c[i][j] = zero; }

  auto stage = [&](int buf, int kt) {
    char* b = &AB[buf][0] + w * 1024;
    async16(gAh0 + kt, b);
    async16(gAh1 + kt, b + 4096);
    async16(gAl0 + kt, b + 8192);
    async16(gAl1 + kt, b + 8192 + 4096);
    async16(gBh0 + kt, b + 16384);
    async16(gBh1 + kt, b + 16384 + 4096);
    async16(gBl0 + kt, b + 24576);
    async16(gBl1 + kt, b + 24576 + 4096);
  };
  auto computeTile = [&](int cur) {
    const char* base = &AB[cur][0];
    f16x8 ah[4], bh[4], tmp[4];
#pragma unroll
    for (int i = 0; i < 4; i++) {
      int ar = wr + i * 16 + l15;
      ah[i] = *(const f16x8*)(base + ar * 64 + ((ls ^ ((ar >> 1) & 3)) << 4));
    }
#pragma unroll
    for (int j = 0; j < 4; j++) {
      int br = wc + j * 16 + l15;
      bh[j] = *(const f16x8*)(base + 16384 + br * 64 + ((ls ^ ((br >> 1) & 3)) << 4));
    }
#pragma unroll
    for (int i = 0; i < 4; i++)
#pragma unroll
      for (int j = 0; j < 4; j++)
        acc_hh[i][j] = __builtin_amdgcn_mfma_f32_16x16x32_f16(ah[i], bh[j], acc_hh[i][j], 0, 0, 0);
#pragma unroll
    for (int j = 0; j < 4; j++) {
      int br = wc + j * 16 + l15;
      tmp[j] = *(const f16x8*)(base + 24576 + br * 64 + ((ls ^ ((br >> 1) & 3)) << 4));
    }
#pragma unroll
    for (int i = 0; i < 4; i++)
#pragma unroll
      for (int j = 0; j < 4; j++)
        acc_c[i][j] = __builtin_amdgcn_mfma_f32_16x16x32_f16(ah[i], tmp[j], acc_c[i][j], 0, 0, 0);
#pragma unroll
    for (int i = 0; i < 4; i++) {
      int ar = wr + i * 16 + l15;
      tmp[i] = *(const f16x8*)(base + 8192 + ar * 64 + ((ls ^ ((ar >> 1) & 3)) << 4));
    }
#pragma unroll
    for (int i = 0; i < 4; i++)
#pragma unroll
      for (int j = 0; j < 4; j++)
        acc_c[i][j] = __builtin_amdgcn_mfma_f32_16x16x32_f16(tmp[i], bh[j], acc_c[i][j], 0, 0, 0);
  };

  const int NIT = DM / 32;
  stage(0, 0);
  __syncthreads();
#pragma unroll 2
  for (int t = 0; t < NIT - 1; t++) {
    const int cur = t & 1;
    stage(cur ^ 1, (t + 1) * 32);
    computeTile(cur);
    __syncthreads();
  }
  computeTile((NIT - 1) & 1);

  float w2r[4][8];
  float bias[4];
#pragma unroll
  for (int j = 0; j < 4; j++) {
    int gn = n0 + wc + j * 16 + l15;
    bias[j] = bg1[gn];
    float4 u = *(const float4*)(Wg2 + (size_t)gn * NE);
    float4 v = *(const float4*)(Wg2 + (size_t)gn * NE + 4);
    w2r[j][0] = u.x; w2r[j][1] = u.y; w2r[j][2] = u.z; w2r[j][3] = u.w;
    w2r[j][4] = v.x; w2r[j][5] = v.y; w2r[j][6] = v.z; w2r[j][7] = v.w;
  }
  const float inv2k = 1.0f / 2048.0f;
  const int half = wc >> 6;
  const bool b3 = (l15 & 8) != 0, b2 = (l15 & 4) != 0, b1 = (l15 & 2) != 0;
#pragma unroll
  for (int i = 0; i < 4; i++) {
#pragma unroll
    for (int r = 0; r < 4; r++) {
      float s[8] = {0.f, 0.f, 0.f, 0.f, 0.f, 0.f, 0.f, 0.f};
#pragma unroll
      for (int j = 0; j < 4; j++) {
        float hv = tanh_fast(acc_hh[i][j][r] + acc_c[i][j][r] * inv2k + bias[j]);
#pragma unroll
        for (int e = 0; e < NE; e++) s[e] = fmaf(hv, w2r[j][e], s[e]);
      }
      float t4_[4], t2_[2], t1_;
#pragma unroll
      for (int q = 0; q < 4; q++) {
        float snd = b3 ? s[q] : s[q + 4];
        float rcv = __shfl_xor(snd, 8);
        t4_[q] = (b3 ? s[q + 4] : s[q]) + rcv;
      }
#pragma unroll
      for (int q = 0; q < 2; q++) {
        float snd = b2 ? t4_[q] : t4_[q + 2];
        float rcv = __shfl_xor(snd, 4);
        t2_[q] = (b2 ? t4_[q + 2] : t4_[q]) + rcv;
      }
      {
        float snd = b1 ? t2_[0] : t2_[1];
        float rcv = __shfl_xor(snd, 2);
        t1_ = (b1 ? t2_[1] : t2_[0]) + rcv;
      }
      t1_ += __shfl_xor(t1_, 1);
      int m = wr + i * 16 + ls * 4 + r;
      if (!(l15 & 1)) lgt[m * (2 * NE) + half * NE + (l15 >> 1)] = t1_;
    }
  }
  __syncthreads();
#pragma unroll
  for (int q = 0; q < 4; q++) {
    int idx = tid * 4 + q;
    int m = idx >> 3, e = idx & 7;
    float v = lgt[m * (2 * NE) + e] + lgt[m * (2 * NE) + NE + e];
    atomicAdd(&logits[(size_t)(m0 + m) * NE + e], v);
  }
}

// ---------------- top-2 over 8 logits per token ----------------
__global__ __launch_bounds__(256) void topk_small_kernel(
    const float* __restrict__ logits, int* __restrict__ tIdx, float* __restrict__ tGate,
    int* __restrict__ counts) {
  __shared__ int lc[NE];
  const int tid = threadIdx.x;
  if (tid < NE) lc[tid] = 0;
  __syncthreads();
  int t = blockIdx.x * 256 + tid;
  float p[NE];
  float4 p0 = *(const float4*)(logits + (size_t)t * NE);
  float4 p1 = *(const float4*)(logits + (size_t)t * NE + 4);
  p[0] = p0.x; p[1] = p0.y; p[2] = p0.z; p[3] = p0.w;
  p[4] = p1.x; p[5] = p1.y; p[6] = p1.z; p[7] = p1.w;
  float v1 = -1e30f, v2 = -1e30f; int i1 = 0, i2 = 1;
#pragma unroll
  for (int e = 0; e < NE; e++) {
    float v = p[e];
    if (v > v1) { v2 = v1; i2 = i1; v1 = v; i1 = e; }
    else if (v > v2) { v2 = v; i2 = e; }
  }
  float mx = v1;
  float s = 0.f;
#pragma unroll
  for (int e = 0; e < NE; e++) s += __expf(p[e] - mx);
  float inv = 1.f / s;
  float g1 = __expf(p[i1] - mx) * inv;
  float g2 = __expf(p[i2] - mx) * inv;
  float den = 1.f / (g1 + g2 + 1e-6f);
  tIdx[2 * t] = i1; tIdx[2 * t + 1] = i2;
  tGate[2 * t] = g1 * den; tGate[2 * t + 1] = g2 * den;
  atomicAdd(&lc[i1], 1);
  atomicAdd(&lc[i2], 1);
  __syncthreads();
  if (tid < NE) atomicAdd(&counts[tid], lc[tid]);
}

// ---------------- prefix sums + tile descriptors (single thread) ----------------
__global__ void build_tiles_kernel(const int* __restrict__ counts, int* __restrict__ offsets,
                                   int4* __restrict__ desc, int* __restrict__ nTiles) {
  if (threadIdx.x != 0 || blockIdx.x != 0) return;
  int off = 0, nt = 0;
  for (int e = 0; e < NE; e++) {
    offsets[e] = off;
    int c = counts[e];
    if (c < 0) c = 0;
    if (c > 2 * T_TOK) c = 2 * T_TOK;
    for (int r = 0; r < c && nt < MAX_TILES; r += 128) {
      int v = c - r; if (v > 128) v = 128;
      desc[nt++] = make_int4(e, off + r, v, 0);
    }
    off += c;
    if (off > 2 * T_TOK) off = 2 * T_TOK;
  }
  offsets[NE] = off;
  *nTiles = nt;
}

// ---------------- scatter tokens into expert-grouped lists ----------------
__global__ void scatter_kernel(const int* __restrict__ tIdx, const float* __restrict__ tGate,
                               const int* __restrict__ offsets, int* __restrict__ fill,
                               int* __restrict__ tokList, float* __restrict__ gateList) {
  int id = blockIdx.x * blockDim.x + threadIdx.x;
  if (id >= 2 * T_TOK) return;
  int e = tIdx[id] & 7;
  int pos = atomicAdd(&fill[e], 1);
  int row = offsets[e] + pos;
  if (row < 0 || row >= 2 * T_TOK) return;
  tokList[row] = id >> 1;
  gateList[row] = tGate[id];
}

// ---------------- FFN1: h = gelu(gather(xb) @ W1_e), BK=32, 3-buf counted-vmcnt, XCD-affine ----------------
__global__ __launch_bounds__(256) void ffn1_kernel(
    const unsigned short* __restrict__ xb, const unsigned short* __restrict__ w1t,
    const int* __restrict__ tokList, const int4* __restrict__ desc,
    const int* __restrict__ nTiles, unsigned short* __restrict__ h) {
  const int g = blockIdx.x;
  const int tileIdx = (g & 7) * TPX + ((g >> 3) % TPX);
  const int nb = g / (8 * TPX);
  if (tileIdx >= *nTiles) return;
  int4 d = desc[tileIdx];
  const int e = d.x, rowStart = d.y, valid = d.z;
  const int n0 = nb * 128;

  __shared__ __align__(16) char AB[3][16384];  // 3-deep pipeline

  const int tid = threadIdx.x;
  const int lane = tid & 63;
  const int w = tid >> 6;

  const int r0 = w * 16 + (lane >> 2);
  const int r1 = r0 + 64;
  const int sp = lane & 3;
  const int k0s = (sp ^ ((r0 >> 1) & 3)) * 8;
  const int k1s = (sp ^ ((r1 >> 1) & 3)) * 8;

  const unsigned short* gA0 = xb + (size_t)(tokList[rowStart + r0] & (T_TOK - 1)) * DM + k0s;
  const unsigned short* gA1 = xb + (size_t)(tokList[rowStart + r1] & (T_TOK - 1)) * DM + k1s;
  const unsigned short* gB0 = w1t + ((size_t)e * DFF + n0 + r0) * DM + k0s;
  const unsigned short* gB1 = w1t + ((size_t)e * DFF + n0 + r1) * DM + k1s;

  const int wr = (w >> 1) * 64, wc = (w & 1) * 64;
  const int l15 = lane & 15, ls = lane >> 4;

  f32x4 zero = {0.f, 0.f, 0.f, 0.f};
  f32x4 acc[4][4];
#pragma unroll
  for (int i = 0; i < 4; i++)
#pragma unroll
    for (int j = 0; j < 4; j++) acc[i][j] = zero;

  auto stage = [&](int buf, int kt) {  // 4 loads per wave per call
    char* dA = &AB[buf][0] + w * 1024;
    char* dB = dA + 8192;
    async16(gA0 + kt, dA);
    async16(gA1 + kt, dA + 4096);
    async16(gB0 + kt, dB);
    async16(gB1 + kt, dB + 4096);
  };
  auto computeTile = [&](int cur) {
    const char* rA = &AB[cur][0];
    const char* rB = rA + 8192;
    bf16x8 af[4], bfv[4];
#pragma unroll
    for (int i = 0; i < 4; i++) {
      int ar = wr + i * 16 + l15;
      af[i] = *(const bf16x8*)(rA + ar * 64 + ((ls ^ ((ar >> 1) & 3)) << 4));
    }
#pragma unroll
    for (int j = 0; j < 4; j++) {
      int br = wc + j * 16 + l15;
      bfv[j] = *(const bf16x8*)(rB + br * 64 + ((ls ^ ((br >> 1) & 3)) << 4));
    }
#pragma unroll
    for (int i = 0; i < 4; i++)
#pragma unroll
      for (int j = 0; j < 4; j++)
        acc[i][j] = __builtin_amdgcn_mfma_f32_16x16x32_bf16(af[i], bfv[j], acc[i][j], 0, 0, 0);
  };

  const int NIT = DM / 32;
  stage(0, 0);
  stage(1, 32);
  int cur = 0, stg = 2;
  for (int t = 0; t < NIT; t++) {
    // counted wait: own 4 oldest loads (tile t) landed; newer prefetch stays in flight
    if (t < NIT - 1) asm volatile("s_waitcnt vmcnt(4)" ::: "memory");
    else             asm volatile("s_waitcnt vmcnt(0)" ::: "memory");
    __builtin_amdgcn_s_barrier();            // publish tile t to all waves
    __builtin_amdgcn_sched_barrier(0);       // keep ds_reads below the barrier
    if (t < NIT - 2) {                       // overwrite of buf read at t-1: barrier above separates
      stage(stg, (t + 2) * 32);
      stg = (stg == 2) ? 0 : stg + 1;
    }
    computeTile(cur);
    cur = (cur == 2) ? 0 : cur + 1;
  }

#pragma unroll
  for (int i = 0; i < 4; i++) {
#pragma unroll
    for (int r = 0; r < 4; r++) {
      int m = wr + i * 16 + ls * 4 + r;
      if (m < valid) {
        size_t base = (size_t)(rowStart + m) * DFF + n0 + wc;
#pragma unroll
        for (int j = 0; j < 4; j++) {
          h[base + j * 16 + l15] = f2b(gelu_fast(acc[i][j][r]));
        }
      }
    }
  }
}

// ---------------- FFN2: y += gate * (h @ W2_e), BK=32, 3-buf counted-vmcnt, XCD-affine ----------------
__global__ __launch_bounds__(256) void ffn2_kernel(
    const unsigned short* __restrict__ h, const unsigned short* __restrict__ w2t,
    const int* __restrict__ tokList, const float* __restrict__ gateList,
    const int4* __restrict__ desc, const int* __restrict__ nTiles,
    float* __restrict__ y) {
  const int g = blockIdx.x;
  const int tileIdx = (g & 7) * TPX + ((g >> 3) % TPX);
  const int nb = g / (8 * TPX);
  if (tileIdx >= *nTiles) return;
  int4 d = desc[tileIdx];
  const int e = d.x, rowStart = d.y, valid = d.z;
  const int n0 = nb * 128;

  __shared__ __align__(16) char AB[3][16384];

  const int tid = threadIdx.x;
  const int lane = tid & 63;
  const int w = tid >> 6;

  const int r0 = w * 16 + (lane >> 2);
  const int r1 = r0 + 64;
  const int sp = lane & 3;
  const int k0s = (sp ^ ((r0 >> 1) & 3)) * 8;
  const int k1s = (sp ^ ((r1 >> 1) & 3)) * 8;

  const unsigned short* gA0 = h + (size_t)(rowStart + r0) * DFF + k0s;
  const unsigned short* gA1 = h + (size_t)(rowStart + r1) * DFF + k1s;
  const unsigned short* gB0 = w2t + ((size_t)e * DM + n0 + r0) * DFF + k0s;
  const unsigned short* gB1 = w2t + ((size_t)e * DM + n0 + r1) * DFF + k1s;

  const int wr = (w >> 1) * 64, wc = (w & 1) * 64;
  const int l15 = lane & 15, ls = lane >> 4;

  f32x4 zero = {0.f, 0.f, 0.f, 0.f};
  f32x4 acc[4][4];
#pragma unroll
  for (int i = 0; i < 4; i++)
#pragma unroll
    for (int j = 0; j < 4; j++) acc[i][j] = zero;

  auto stage = [&](int buf, int kt) {
    char* dA = &AB[buf][0] + w * 1024;
    char* dB = dA + 8192;
    async16(gA0 + kt, dA);
    async16(gA1 + kt, dA + 4096);
    async16(gB0 + kt, dB);
    async16(gB1 + kt, dB + 4096);
  };
  auto computeTile = [&](int cur) {
    const char* rA = &AB[cur][0];
    const char* rB = rA + 8192;
    bf16x8 af[4], bfv[4];
#pragma unroll
    for (int i = 0; i < 4; i++) {
      int ar = wr + i * 16 + l15;
      af[i] = *(const bf16x8*)(rA + ar * 64 + ((ls ^ ((ar >> 1) & 3)) << 4));
    }
#pragma unroll
    for (int j = 0; j < 4; j++) {
      int br = wc + j * 16 + l15;
      bfv[j] = *(const bf16x8*)(rB + br * 64 + ((ls ^ ((br >> 1) & 3)) << 4));
    }
#pragma unroll
    for (int i = 0; i < 4; i++)
#pragma unroll
      for (int j = 0; j < 4; j++)
        acc[i][j] = __builtin_amdgcn_mfma_f32_16x16x32_bf16(af[i], bfv[j], acc[i][j], 0, 0, 0);
  };

  const int NIT = DFF / 32;
  stage(0, 0);
  stage(1, 32);
  int cur = 0, stg = 2;
  for (int t = 0; t < NIT; t++) {
    if (t < NIT - 1) asm volatile("s_waitcnt vmcnt(4)" ::: "memory");
    else             asm volatile("s_waitcnt vmcnt(0)" ::: "memory");
    __builtin_amdgcn_s_barrier();
    __builtin_amdgcn_sched_barrier(0);
    if (t < NIT - 2) {
      stage(stg, (t + 2) * 32);
      stg = (stg == 2) ? 0 : stg + 1;
    }
    computeTile(cur);
    cur = (cur == 2) ? 0 : cur + 1;
  }

#pragma unroll
  for (int i = 0; i < 4; i++) {
#pragma unroll
    for (int r = 0; r < 4; r++) {
      int m = wr + i * 16 + ls * 4 + r;
      if (m < valid) {
        int row = rowStart + m;
        int tok = tokList[row] & (T_TOK - 1);
        float g2 = gateList[row];
        float* yr = y + (size_t)tok * DM + n0 + wc;
#pragma unroll
        for (int j = 0; j < 4; j++) {
          atomicAdd(&yr[j * 16 + l15], g2 * acc[i][j][r]);
        }
      }
    }
  }
}

// ---------------- host launch ----------------
extern "C" void kernel_launch(void* const* d_in, const int* in_sizes, int n_in,
                              void* d_out, int out_size, void* d_ws, size_t ws_size,
                              hipStream_t stream) {
  const float* x   = (const float*)d_in[0];
  const float* Wg1 = (const float*)d_in[1];
  const float* bg1 = (const float*)d_in[2];
  const float* Wg2 = (const float*)d_in[3];
  const float* W1  = (const float*)d_in[4];
  const float* W2  = (const float*)d_in[5];
  float* y = (float*)d_out;
  char* ws = (char*)d_ws;

  const size_t SZ_W1T = (size_t)NE * DFF * DM * 2;
  const size_t OFF_W1T = 0;
  const size_t OFF_W2T = OFF_W1T + SZ_W1T;
  const size_t OFF_XB  = OFF_W2T + SZ_W1T;
  const size_t OFF_H   = OFF_XB + (size_t)T_TOK * DM * 2;
  const size_t OFF_TOK = OFF_H + (size_t)HROWS * DFF * 2;
  const size_t OFF_GATE = OFF_TOK + (size_t)HROWS * 4;
  const size_t OFF_TIDX = OFF_GATE + (size_t)HROWS * 4;
  const size_t OFF_TG   = OFF_TIDX + (size_t)2 * T_TOK * 4;
  const size_t OFF_LOG  = OFF_TG + (size_t)2 * T_TOK * 4;
  const size_t OFF_META = OFF_LOG + (size_t)T_TOK * NE * 4;
  const size_t NEED = OFF_META + 4096;

  const size_t OFF_XH  = OFF_H;
  const size_t OFF_XL  = OFF_XH + (size_t)T_TOK * DM * 2;
  const size_t OFF_WTH = OFF_XL + (size_t)T_TOK * DM * 2;
  const size_t OFF_WTL = OFF_WTH + (size_t)DM * DM * 2;

  hipMemsetAsync(d_out, 0, (size_t)out_size * 4, stream);
  if (ws_size < NEED) return;

  unsigned short* w1t = (unsigned short*)(ws + OFF_W1T);
  unsigned short* w2t = (unsigned short*)(ws + OFF_W2T);
  unsigned short* xb  = (unsigned short*)(ws + OFF_XB);
  unsigned short* h   = (unsigned short*)(ws + OFF_H);
  _Float16* xh        = (_Float16*)(ws + OFF_XH);
  _Float16* xl        = (_Float16*)(ws + OFF_XL);
  _Float16* wth       = (_Float16*)(ws + OFF_WTH);
  _Float16* wtl       = (_Float16*)(ws + OFF_WTL);
  int* tokList        = (int*)(ws + OFF_TOK);
  float* gateList     = (float*)(ws + OFF_GATE);
  int* tIdx           = (int*)(ws + OFF_TIDX);
  float* tGate        = (float*)(ws + OFF_TG);
  float* logits       = (float*)(ws + OFF_LOG);
  int* counts         = (int*)(ws + OFF_META);
  int* fill           = (int*)(ws + OFF_META + 32);
  int* offsets        = (int*)(ws + OFF_META + 64);
  int* nTiles         = (int*)(ws + OFF_META + 128);
  int4* desc          = (int4*)(ws + OFF_META + 160);

  hipMemsetAsync(ws + OFF_TOK, 0, (size_t)2 * HROWS * 4, stream);
  hipMemsetAsync(ws + OFF_LOG, 0, (size_t)T_TOK * NE * 4, stream);
  hipMemsetAsync(ws + OFF_META, 0, 64, stream);

  split_x_kernel<<<dim3((T_TOK * DM / 4) / 256), dim3(256), 0, stream>>>(x, xb, xh, xl);
  transpose_split_w_kernel<<<dim3(DM / 32, DM / 32), dim3(32, 8), 0, stream>>>(Wg1, wth, wtl);
  transpose_cast_kernel<<<dim3(DFF / 32, DM / 32, NE), dim3(32, 8), 0, stream>>>(W1, w1t, DM, DFF);
  transpose_cast_kernel<<<dim3(DM / 32, DFF / 32, NE), dim3(32, 8), 0, stream>>>(W2, w2t, DFF, DM);

  router_mfma_kernel<<<dim3(DM / 128, T_TOK / 128), dim3(256), 0, stream>>>(xh, xl, wth, wtl,
                                                                            bg1, Wg2, logits);
  topk_small_kernel<<<dim3(T_TOK / 256), dim3(256), 0, stream>>>(logits, tIdx, tGate, counts);
  build_tiles_kernel<<<dim3(1), dim3(64), 0, stream>>>(counts, offsets, desc, nTiles);
  scatter_kernel<<<dim3((2 * T_TOK) / 256), dim3(256), 0, stream>>>(tIdx, tGate, offsets, fill,
                                                                    tokList, gateList);

  ffn1_kernel<<<dim3((DFF / 128) * MAX_TILES), dim3(256), 0, stream>>>(xb, w1t, tokList, desc,
                                                                       nTiles, h);
  ffn2_kernel<<<dim3((DM / 128) * MAX_TILES), dim3(256), 0, stream>>>(h, w2t, tokList, gateList,
                                                                      desc, nTiles, y);
}